// Round 14
// baseline (4040.883 us; speedup 1.0000x reference)
//
#include <hip/hip_runtime.h>
#include <hip/hip_bf16.h>

#define B_ROWS 16384
#define M_DIM  256
#define N_DIM  1024
#define DEPTH  16

typedef __attribute__((ext_vector_type(8))) short short8;
typedef __attribute__((ext_vector_type(4))) float f32x4;

// ---------------- fast path ws layout (bytes) ----------------
#define ATP_OFF_B   0
#define WTP_OFF_B   1572864
#define WS_FAST_NEED ((size_t)WTP_OFF_B + 25165824)
#define WTP_SLICE   (64 * 8 * 3 * 512)              // ushorts per iteration

// ---------------- fallback (round-3) ws layout ----------------
#define AT_OFF 0
#define WT_OFF (262144)
#define WS_OLD_NEED ((size_t)(262144 + 16 * 262144) * 4)

// ================= helpers =================
__device__ __forceinline__ unsigned short bf16r(float f) {
    unsigned u = __float_as_uint(f);
    u += 0x7fffu + ((u >> 16) & 1u);
    return (unsigned short)(u >> 16);
}
__device__ __forceinline__ float bf2f(unsigned short h) {
    return __uint_as_float(((unsigned)h) << 16);
}
__device__ __forceinline__ void split3(float x, unsigned short& h, unsigned short& m,
                                       unsigned short& lo) {
    h = bf16r(x); float r1 = x - bf2f(h);
    m = bf16r(r1); float r2 = r1 - bf2f(m);
    lo = bf16r(r2);
}
__device__ __forceinline__ f32x4 MF(short8 a, short8 b, f32x4 c) {
    return __builtin_amdgcn_mfma_f32_16x16x32_bf16(a, b, c, 0, 0, 0);
}
__device__ __forceinline__ float shrink_one(float v, float t, float thrv) {
    float a = fabsf(v);
    return (a >= thrv) ? v : copysignf(fmaxf(a - t, 0.0f), v);
}

// ================= prep kernels (frag-ordered bf16 planes) =================
__global__ void prep_a_kernel(const float* __restrict__ A, unsigned short* __restrict__ ATp) {
    int g = blockIdx.x * 256 + threadIdx.x;
    if (g >= 16 * 32 * 64) return;
    int l = g & 63, kc = (g >> 6) & 31, tile = g >> 11;
    int row = tile * 16 + (l & 15);
    int k0 = kc * 32 + ((l >> 4) << 3);
    unsigned short h[8], m[8], lo[8];
#pragma unroll
    for (int j = 0; j < 8; ++j) split3(A[(size_t)row * N_DIM + k0 + j], h[j], m[j], lo[j]);
    size_t base = ((size_t)(tile * 32 + kc) * 3) * 512 + l * 8;
#pragma unroll
    for (int j = 0; j < 8; ++j) {
        ATp[base + j] = h[j];
        ATp[base + 512 + j] = m[j];
        ATp[base + 1024 + j] = lo[j];
    }
}

__global__ void prep_w_kernel(const float* __restrict__ W, unsigned short* __restrict__ WTp) {
    int g = blockIdx.x * 256 + threadIdx.x;
    if (g >= 16 * 64 * 8 * 64) return;
    int l = g & 63, kc = (g >> 6) & 7, tile = (g >> 9) & 63, it = g >> 15;
    int n = tile * 16 + (l & 15);
    int m0 = kc * 32 + ((l >> 4) << 3);
    const float* Wi = W + (size_t)it * N_DIM * M_DIM;
    unsigned short h[8], m[8], lo[8];
#pragma unroll
    for (int j = 0; j < 8; ++j) split3(Wi[(size_t)n * M_DIM + m0 + j], h[j], m[j], lo[j]);
    size_t base = (((size_t)(it * 64 + tile) * 8 + kc) * 3) * 512 + l * 8;
#pragma unroll
    for (int j = 0; j < 8; ++j) {
        WTp[base + j] = h[j];
        WTp[base + 512 + j] = m[j];
        WTp[base + 1024 + j] = lo[j];
    }
}

// ================= MEGA: all 16 iterations, u resident in registers =================
// grid 1024 (16-row panels), 512 threads (8 waves). Wave w owns rows {2w,2w+1};
// lane l holds cols l+64*j (j=0..15). LDS: staging dbuf 2x6528us overlapped with
// r-frag img 12288us, + vbuf f32[16][132] @ us 26112. Total 60672 B.
// Weights (ATp/WTp frag planes) stream from L2/L3. No UV/RP state traffic.
__global__ __launch_bounds__(512)
void mega_kernel(const float* __restrict__ x, const unsigned short* __restrict__ ATp,
                 const unsigned short* __restrict__ WTp, const float* __restrict__ thr_all,
                 float* __restrict__ UV) {
    __align__(16) __shared__ unsigned short smem[30336];
    float* vbuf = (float*)&smem[26112];          // [16][132] padded
    const int tid = threadIdx.x;
    const int l = tid & 63, w = tid >> 6;        // 8 waves
    const int row0 = blockIdx.x * 16;
    const int arow = l & 15;
    const int akl  = (l >> 4) << 3;

    float u0[16], u1[16];                        // rows 2w, 2w+1
#pragma unroll
    for (int j = 0; j < 16; ++j) { u0[j] = 0.0f; u1[j] = 0.0f; }

#pragma unroll 1
    for (int it = 0; it < DEPTH; ++it) {
        // ================= Phase R: build r-frag img in LDS =================
        if (it == 0) {
            // r = x: stage split3(x) directly into img
            const int kcp = (tid >> 6) & 3, cc = (tid >> 8) & 1;
            const int row = row0 + (l & 15);
            const int k0 = cc * 128 + kcp * 32 + akl;
            const unsigned base = ((unsigned)(cc * 4 + kcp) * 3) * 512 + (unsigned)l * 8;
#pragma unroll
            for (int j = 0; j < 8; ++j) {
                unsigned short h, m, lo;
                split3(x[(size_t)row * M_DIM + k0 + j], h, m, lo);
                smem[base + j] = h;
                smem[base + 512 + j] = m;
                smem[base + 1024 + j] = lo;
            }
            __syncthreads();
        } else {
            f32x4 acc_hi[2], acc_rest[2];
            double acc64[2][4];
#pragma unroll
            for (int t = 0; t < 2; ++t) {
                acc_hi[t] = (f32x4){0, 0, 0, 0};
                acc_rest[t] = (f32x4){0, 0, 0, 0};
#pragma unroll
                for (int e = 0; e < 4; ++e) acc64[t][e] = 0.0;
            }
            // prefetch x for epilogue (L2-resident after it=0)
            float xr[2][4];
#pragma unroll
            for (int tt = 0; tt < 2; ++tt) {
                const int col = (w * 2 + tt) * 16 + (l & 15);
#pragma unroll
                for (int e = 0; e < 4; ++e) {
                    const int mi = ((l >> 4) << 2) + e;
                    xr[tt][e] = x[(size_t)(row0 + mi) * M_DIM + col];
                }
            }
            // stage chunk 0 from regs -> buf0
#pragma unroll
            for (int rr = 0; rr < 2; ++rr) {
#pragma unroll
                for (int jj = 0; jj < 2; ++jj) {
                    const float uval = rr ? u1[jj] : u0[jj];
                    unsigned short h, m, lo;
                    split3(uval, h, m, lo);
                    const unsigned off = (unsigned)(2 * w + rr) * 136 + l + 64 * jj;
                    smem[off] = h;
                    smem[off + 2176] = m;
                    smem[off + 4352] = lo;
                }
            }
            __syncthreads();
#pragma unroll
            for (int c = 0; c < 8; ++c) {
                const unsigned bb = (c & 1) ? 6528u : 0u;
                if (c < 7) {   // stage chunk c+1 into the other buffer (regs, no loads)
                    const unsigned nb = (c & 1) ? 0u : 6528u;
#pragma unroll
                    for (int rr = 0; rr < 2; ++rr) {
#pragma unroll
                        for (int jj = 0; jj < 2; ++jj) {
                            const float uval = rr ? u1[2 * (c + 1) + jj] : u0[2 * (c + 1) + jj];
                            unsigned short h, m, lo;
                            split3(uval, h, m, lo);
                            const unsigned off = nb + (unsigned)(2 * w + rr) * 136 + l + 64 * jj;
                            smem[off] = h;
                            smem[off + 2176] = m;
                            smem[off + 4352] = lo;
                        }
                    }
                }
#pragma unroll
                for (int kc = 0; kc < 4; ++kc) {
                    const unsigned ao = bb + (unsigned)arow * 136 + kc * 32 + akl;
                    short8 ah = *(const short8*)&smem[ao];
                    short8 am = *(const short8*)&smem[ao + 2176];
                    short8 al = *(const short8*)&smem[ao + 4352];
#pragma unroll
                    for (int tt = 0; tt < 2; ++tt) {
                        const int tile = w * 2 + tt;
                        const unsigned bo = ((unsigned)(tile * 32 + c * 4 + kc) * 3) * 512 + l * 8;
                        short8 bh = *(const short8*)&ATp[bo];
                        short8 bm = *(const short8*)&ATp[bo + 512];
                        short8 bl = *(const short8*)&ATp[bo + 1024];
                        acc_hi[tt] = MF(ah, bh, acc_hi[tt]);
                        acc_rest[tt] = MF(ah, bm, acc_rest[tt]);
                        acc_rest[tt] = MF(am, bh, acc_rest[tt]);
                        acc_rest[tt] = MF(am, bm, acc_rest[tt]);
                        acc_rest[tt] = MF(ah, bl, acc_rest[tt]);
                        acc_rest[tt] = MF(al, bh, acc_rest[tt]);
                    }
                }
#pragma unroll
                for (int tt = 0; tt < 2; ++tt) {   // drain once per 128-k chunk
#pragma unroll
                    for (int e = 0; e < 4; ++e) acc64[tt][e] += (double)acc_hi[tt][e];
                    acc_hi[tt] = (f32x4){0, 0, 0, 0};
                }
                __syncthreads();
            }
            // epilogue: r = x - acc -> split3 -> img
#pragma unroll
            for (int tt = 0; tt < 2; ++tt) {
                const int ki = (w * 2 + tt) * 16 + (l & 15);
                const unsigned slb = ((unsigned)(ki >> 5) * 3) * 512 +
                                     ((unsigned)((ki >> 3) & 3) * 16) * 8 + (ki & 7);
#pragma unroll
                for (int e = 0; e < 4; ++e) {
                    const int mi = ((l >> 4) << 2) + e;
                    const double tot = acc64[tt][e] + (double)acc_rest[tt][e];
                    const float rv = (float)((double)xr[tt][e] - tot);
                    unsigned short h, m, lo;
                    split3(rv, h, m, lo);
                    const unsigned sl = slb + (unsigned)mi * 8;
                    smem[sl] = h;
                    smem[sl + 512] = m;
                    smem[sl + 1024] = lo;
                }
            }
            __syncthreads();
        }

        // ================= Phase V: v = u + r * W_it^T ; select ; shrink =================
        const unsigned short* WTpi = WTp + (size_t)it * WTP_SLICE;
#pragma unroll
        for (int g = 0; g < 8; ++g) {
            f32x4 hi = (f32x4){0, 0, 0, 0};
            f32x4 rest = (f32x4){0, 0, 0, 0};
            f32x4 sum = (f32x4){0, 0, 0, 0};
            const int tile = g * 8 + w;
#pragma unroll
            for (int kc = 0; kc < 8; ++kc) {
                const unsigned ab = ((unsigned)kc * 3) * 512 + l * 8;
                short8 ah = *(const short8*)&smem[ab];
                short8 am = *(const short8*)&smem[ab + 512];
                short8 al = *(const short8*)&smem[ab + 1024];
                const unsigned bo = ((unsigned)(tile * 8 + kc) * 3) * 512 + l * 8;
                short8 bh = *(const short8*)&WTpi[bo];
                short8 bm = *(const short8*)&WTpi[bo + 512];
                short8 bl = *(const short8*)&WTpi[bo + 1024];
                hi = MF(ah, bh, hi);
                rest = MF(ah, bm, rest);
                rest = MF(am, bh, rest);
                rest = MF(am, bm, rest);
                rest = MF(ah, bl, rest);
                rest = MF(al, bh, rest);
                if ((kc & 3) == 3) {
#pragma unroll
                    for (int e = 0; e < 4; ++e) sum[e] += hi[e];
                    hi = (f32x4){0, 0, 0, 0};
                }
            }
#pragma unroll
            for (int e = 0; e < 4; ++e) {
                const int mi = ((l >> 4) << 2) + e;
                vbuf[mi * 132 + w * 16 + (l & 15)] = sum[e] + rest[e];
            }
            __syncthreads();
#pragma unroll
            for (int jj = 0; jj < 2; ++jj) {
                u0[g * 2 + jj] += vbuf[(2 * w) * 132 + l + 64 * jj];
                u1[g * 2 + jj] += vbuf[(2 * w + 1) * 132 + l + 64 * jj];
            }
            __syncthreads();
        }

        // select tau (exact k-th largest of |v| per row) + shrink, in registers
        const float t = thr_all[it];
        const int kth = (it >= 4) ? 52 : ((it == 3) ? 50 : 13 + 12 * it);
        {
            unsigned key[16];
#pragma unroll
            for (int j = 0; j < 16; ++j) key[j] = __float_as_uint(u0[j]) & 0x7fffffffu;
            unsigned p = 0;
#pragma unroll 1
            for (int b = 30; b >= 0; --b) {
                const unsigned cand = p | (1u << b);
                int cnt = 0;
#pragma unroll
                for (int j = 0; j < 16; ++j) cnt += __popcll(__ballot(key[j] >= cand));
                if (cnt >= kth) p = cand;
            }
            const float thrv = fmaxf(t, __uint_as_float(p));
#pragma unroll
            for (int j = 0; j < 16; ++j) u0[j] = shrink_one(u0[j], t, thrv);
        }
        {
            unsigned key[16];
#pragma unroll
            for (int j = 0; j < 16; ++j) key[j] = __float_as_uint(u1[j]) & 0x7fffffffu;
            unsigned p = 0;
#pragma unroll 1
            for (int b = 30; b >= 0; --b) {
                const unsigned cand = p | (1u << b);
                int cnt = 0;
#pragma unroll
                for (int j = 0; j < 16; ++j) cnt += __popcll(__ballot(key[j] >= cand));
                if (cnt >= kth) p = cand;
            }
            const float thrv = fmaxf(t, __uint_as_float(p));
#pragma unroll
            for (int j = 0; j < 16; ++j) u1[j] = shrink_one(u1[j], t, thrv);
        }
    }

    // final store: u -> d_out (f32, coalesced)
#pragma unroll
    for (int j = 0; j < 16; ++j) {
        UV[(size_t)(row0 + 2 * w) * N_DIM + l + 64 * j] = u0[j];
        UV[(size_t)(row0 + 2 * w + 1) * N_DIM + l + 64 * j] = u1[j];
    }
}

// ===================== round-3 fallback kernels ======================
#define DFMA4(acc, s, v) do { \
    (acc).x += (double)(s) * (double)(v).x; \
    (acc).y += (double)(s) * (double)(v).y; \
    (acc).z += (double)(s) * (double)(v).z; \
    (acc).w += (double)(s) * (double)(v).w; } while (0)

__global__ void transpose_kernel(const float* __restrict__ in, float* __restrict__ out,
                                 int R, int C) {
    __shared__ float tile[32][33];
    int s = blockIdx.z;
    const float* ip = in + (size_t)s * R * C;
    float* op = out + (size_t)s * R * C;
    int c0 = blockIdx.x * 32, r0 = blockIdx.y * 32;
    int tx = threadIdx.x, ty = threadIdx.y;
#pragma unroll
    for (int k = 0; k < 4; ++k)
        tile[ty + 8 * k][tx] = ip[(size_t)(r0 + ty + 8 * k) * C + (c0 + tx)];
    __syncthreads();
#pragma unroll
    for (int k = 0; k < 4; ++k)
        op[(size_t)(c0 + ty + 8 * k) * R + (r0 + tx)] = tile[tx][ty + 8 * k];
}

__global__ void zero_kernel(float* __restrict__ p, int n) {
    int i = blockIdx.x * blockDim.x + threadIdx.x;
    int stride = gridDim.x * blockDim.x;
    for (; i < n; i += stride) p[i] = 0.0f;
}

template <bool T>
__device__ __forceinline__ float4 loadAT(const float* __restrict__ p, int n, int m4) {
    if constexpr (T) {
        return ((const float4*)p)[n * 64 + m4];
    } else {
        float4 r;
        r.x = p[(size_t)(4 * m4 + 0) * N_DIM + n];
        r.y = p[(size_t)(4 * m4 + 1) * N_DIM + n];
        r.z = p[(size_t)(4 * m4 + 2) * N_DIM + n];
        r.w = p[(size_t)(4 * m4 + 3) * N_DIM + n];
        return r;
    }
}
template <bool T>
__device__ __forceinline__ float4 loadWT(const float* __restrict__ p, int m, int n4) {
    if constexpr (T) {
        return ((const float4*)p)[m * 256 + n4];
    } else {
        float4 r;
        r.x = p[(size_t)(4 * n4 + 0) * M_DIM + m];
        r.y = p[(size_t)(4 * n4 + 1) * M_DIM + m];
        r.z = p[(size_t)(4 * n4 + 2) * M_DIM + m];
        r.w = p[(size_t)(4 * n4 + 3) * M_DIM + m];
        return r;
    }
}

template <bool T>
__global__ __launch_bounds__(256)
void lista_iter_kernel(const float* __restrict__ x, const float* __restrict__ Ap,
                       const float* __restrict__ Wp, const float* __restrict__ thr_all,
                       float* __restrict__ U, int iter, int kth) {
    __shared__ float u_s[8][1024];
    __shared__ float r_s[8][256];
    __shared__ float tau_s[8];
    const int tid = threadIdx.x;
    const int lane = tid & 63;
    const int wave = tid >> 6;
    const int row0 = blockIdx.x * 8;
    const float t = thr_all[iter];
    {
        const float4* Ug4 = (const float4*)(U + (size_t)row0 * N_DIM);
        float4* us4 = (float4*)(&u_s[0][0]);
#pragma unroll
        for (int c = 0; c < 8; ++c) us4[tid + 256 * c] = Ug4[tid + 256 * c];
    }
    __syncthreads();
    {
        double4 acc0 = {0, 0, 0, 0}, acc1 = {0, 0, 0, 0};
        const float4* u0p = (const float4*)&u_s[wave][0];
        const float4* u1p = (const float4*)&u_s[wave + 4][0];
        for (int n4 = 0; n4 < 256; ++n4) {
            float4 u0 = u0p[n4];
            float4 u1 = u1p[n4];
            float4 a0 = loadAT<T>(Ap, 4 * n4 + 0, lane);
            float4 a1 = loadAT<T>(Ap, 4 * n4 + 1, lane);
            float4 a2 = loadAT<T>(Ap, 4 * n4 + 2, lane);
            float4 a3 = loadAT<T>(Ap, 4 * n4 + 3, lane);
            DFMA4(acc0, u0.x, a0); DFMA4(acc0, u0.y, a1); DFMA4(acc0, u0.z, a2); DFMA4(acc0, u0.w, a3);
            DFMA4(acc1, u1.x, a0); DFMA4(acc1, u1.y, a1); DFMA4(acc1, u1.z, a2); DFMA4(acc1, u1.w, a3);
        }
        float4 xv0 = ((const float4*)(x + (size_t)(row0 + wave) * M_DIM))[lane];
        float4 xv1 = ((const float4*)(x + (size_t)(row0 + wave + 4) * M_DIM))[lane];
        float4 rv0, rv1;
        rv0.x = (float)((double)xv0.x - acc0.x);
        rv0.y = (float)((double)xv0.y - acc0.y);
        rv0.z = (float)((double)xv0.z - acc0.z);
        rv0.w = (float)((double)xv0.w - acc0.w);
        rv1.x = (float)((double)xv1.x - acc1.x);
        rv1.y = (float)((double)xv1.y - acc1.y);
        rv1.z = (float)((double)xv1.z - acc1.z);
        rv1.w = (float)((double)xv1.w - acc1.w);
        ((float4*)&r_s[wave][0])[lane] = rv0;
        ((float4*)&r_s[wave + 4][0])[lane] = rv1;
    }
    __syncthreads();
    {
        const float4* r0p = (const float4*)&r_s[wave][0];
        const float4* r1p = (const float4*)&r_s[wave + 4][0];
        float4* u0p = (float4*)&u_s[wave][0];
        float4* u1p = (float4*)&u_s[wave + 4][0];
#pragma unroll 1
        for (int q = 0; q < 4; ++q) {
            const int n4 = lane + 64 * q;
            double4 acc0 = {0, 0, 0, 0}, acc1 = {0, 0, 0, 0};
            for (int m4 = 0; m4 < 64; ++m4) {
                float4 r0 = r0p[m4];
                float4 r1 = r1p[m4];
                float4 w0 = loadWT<T>(Wp, 4 * m4 + 0, n4);
                float4 w1 = loadWT<T>(Wp, 4 * m4 + 1, n4);
                float4 w2 = loadWT<T>(Wp, 4 * m4 + 2, n4);
                float4 w3 = loadWT<T>(Wp, 4 * m4 + 3, n4);
                DFMA4(acc0, r0.x, w0); DFMA4(acc0, r0.y, w1); DFMA4(acc0, r0.z, w2); DFMA4(acc0, r0.w, w3);
                DFMA4(acc1, r1.x, w0); DFMA4(acc1, r1.y, w1); DFMA4(acc1, r1.z, w2); DFMA4(acc1, r1.w, w3);
            }
            float4 uv0 = u0p[n4];
            uv0.x = (float)((double)uv0.x + acc0.x);
            uv0.y = (float)((double)uv0.y + acc0.y);
            uv0.z = (float)((double)uv0.z + acc0.z);
            uv0.w = (float)((double)uv0.w + acc0.w);
            u0p[n4] = uv0;
            float4 uv1 = u1p[n4];
            uv1.x = (float)((double)uv1.x + acc1.x);
            uv1.y = (float)((double)uv1.y + acc1.y);
            uv1.z = (float)((double)uv1.z + acc1.z);
            uv1.w = (float)((double)uv1.w + acc1.w);
            u1p[n4] = uv1;
        }
    }
    __syncthreads();
    {
#pragma unroll 1
        for (int rr = 0; rr < 2; ++rr) {
            const int row = wave + rr * 4;
            unsigned key[16];
#pragma unroll
            for (int j = 0; j < 16; ++j)
                key[j] = __float_as_uint(u_s[row][lane + 64 * j]) & 0x7fffffffu;
            unsigned p = 0;
#pragma unroll 1
            for (int b = 30; b >= 0; --b) {
                const unsigned cand = p | (1u << b);
                int cnt = 0;
#pragma unroll
                for (int j = 0; j < 16; ++j) cnt += (key[j] >= cand) ? 1 : 0;
#pragma unroll
                for (int off = 32; off; off >>= 1) cnt += __shfl_xor(cnt, off);
                if (cnt >= kth) p = cand;
            }
            if (lane == 0) tau_s[row] = __uint_as_float(p);
        }
    }
    __syncthreads();
    {
        const float4* us4 = (const float4*)&u_s[0][0];
        float4* Uw = (float4*)(U + (size_t)row0 * N_DIM);
#pragma unroll 1
        for (int c = 0; c < 8; ++c) {
            const int idx = tid + 256 * c;
            const int row = idx >> 8;
            const float thrv = fmaxf(t, tau_s[row]);
            float4 v = us4[idx];
            float4 o;
            o.x = shrink_one(v.x, t, thrv);
            o.y = shrink_one(v.y, t, thrv);
            o.z = shrink_one(v.z, t, thrv);
            o.w = shrink_one(v.w, t, thrv);
            Uw[idx] = o;
        }
    }
}

// ================= launcher =================
extern "C" void kernel_launch(void* const* d_in, const int* in_sizes, int n_in,
                              void* d_out, int out_size, void* d_ws, size_t ws_size,
                              hipStream_t stream) {
    const float* x   = (const float*)d_in[0];  // [16384][256]
    const float* A   = (const float*)d_in[1];  // [256][1024]
    const float* W   = (const float*)d_in[2];  // [16][1024][256]
    const float* thr = (const float*)d_in[3];  // [16]

    float* UV = (float*)d_out;

    static const int ktab[DEPTH] = {13, 25, 37, 50, 52, 52, 52, 52,
                                    52, 52, 52, 52, 52, 52, 52, 52};

    if (ws_size >= WS_FAST_NEED) {
        unsigned short* ATp = (unsigned short*)((char*)d_ws + ATP_OFF_B);
        unsigned short* WTp = (unsigned short*)((char*)d_ws + WTP_OFF_B);

        prep_a_kernel<<<128, 256, 0, stream>>>(A, ATp);
        prep_w_kernel<<<2048, 256, 0, stream>>>(W, WTp);
        mega_kernel<<<B_ROWS / 16, 512, 0, stream>>>(x, ATp, WTp, thr, UV);
    } else if (ws_size >= WS_OLD_NEED) {
        float* ws = (float*)d_ws;
        float* AT = ws + AT_OFF;
        float* WT = ws + WT_OFF;
        zero_kernel<<<1024, 256, 0, stream>>>(UV, B_ROWS * N_DIM);
        dim3 tb(32, 8);
        transpose_kernel<<<dim3(N_DIM / 32, M_DIM / 32, 1), tb, 0, stream>>>(A, AT, M_DIM, N_DIM);
        transpose_kernel<<<dim3(M_DIM / 32, N_DIM / 32, DEPTH), tb, 0, stream>>>(W, WT, N_DIM, M_DIM);
        for (int it = 0; it < DEPTH; ++it)
            lista_iter_kernel<true><<<B_ROWS / 8, 256, 0, stream>>>(
                x, AT, WT + (size_t)it * M_DIM * N_DIM, thr, UV, it, ktab[it]);
    } else {
        zero_kernel<<<1024, 256, 0, stream>>>(UV, B_ROWS * N_DIM);
        for (int it = 0; it < DEPTH; ++it)
            lista_iter_kernel<false><<<B_ROWS / 8, 256, 0, stream>>>(
                x, A, W + (size_t)it * N_DIM * M_DIM, thr, UV, it, ktab[it]);
    }
}

// Round 15
// 3181.011 us; speedup vs baseline: 1.2703x; 1.2703x over previous
//
#include <hip/hip_runtime.h>
#include <hip/hip_bf16.h>

#define B_ROWS 16384
#define M_DIM  256
#define N_DIM  1024
#define DEPTH  16

typedef __attribute__((ext_vector_type(8))) short short8;
typedef __attribute__((ext_vector_type(4))) float f32x4;
typedef __attribute__((ext_vector_type(2))) float f32x2;

// ---------------- fast path ws layout (bytes) ----------------
#define ATP_OFF_B   0
#define WTP_OFF_B   1572864
#define RP_OFF_B    (1572864 + 25165824)
#define WS_FAST_NEED ((size_t)RP_OFF_B + 25165824)
#define WTP_SLICE   (64 * 8 * 3 * 512)              // ushorts per iteration
#define RP_PANEL_US 24576                            // ushorts per 32-row panel (48KB)

// ---------------- fallback (round-3) ws layout ----------------
#define AT_OFF 0
#define WT_OFF (262144)
#define WS_OLD_NEED ((size_t)(262144 + 16 * 262144) * 4)

// ================= helpers =================
__device__ __forceinline__ unsigned short bf16r(float f) {
    unsigned u = __float_as_uint(f);
    u += 0x7fffu + ((u >> 16) & 1u);
    return (unsigned short)(u >> 16);
}
__device__ __forceinline__ float bf2f(unsigned short h) {
    return __uint_as_float(((unsigned)h) << 16);
}
__device__ __forceinline__ void split3(float x, unsigned short& h, unsigned short& m,
                                       unsigned short& lo) {
    h = bf16r(x); float r1 = x - bf2f(h);
    m = bf16r(r1); float r2 = r1 - bf2f(m);
    lo = bf16r(r2);
}
__device__ __forceinline__ f32x4 MF(short8 a, short8 b, f32x4 c) {
    return __builtin_amdgcn_mfma_f32_16x16x32_bf16(a, b, c, 0, 0, 0);
}
__device__ __forceinline__ float shrink_one(float v, float t, float thrv) {
    float a = fabsf(v);
    return (a >= thrv) ? v : copysignf(fmaxf(a - t, 0.0f), v);
}

// ================= prep kernels (frag-ordered bf16 planes) =================
__global__ void prep_a_kernel(const float* __restrict__ A, unsigned short* __restrict__ ATp) {
    int g = blockIdx.x * 256 + threadIdx.x;
    if (g >= 16 * 32 * 64) return;
    int l = g & 63, kc = (g >> 6) & 31, tile = g >> 11;
    int row = tile * 16 + (l & 15);
    int k0 = kc * 32 + ((l >> 4) << 3);
    unsigned short h[8], m[8], lo[8];
#pragma unroll
    for (int j = 0; j < 8; ++j) split3(A[(size_t)row * N_DIM + k0 + j], h[j], m[j], lo[j]);
    size_t base = ((size_t)(tile * 32 + kc) * 3) * 512 + l * 8;
#pragma unroll
    for (int j = 0; j < 8; ++j) {
        ATp[base + j] = h[j];
        ATp[base + 512 + j] = m[j];
        ATp[base + 1024 + j] = lo[j];
    }
}

__global__ void prep_w_kernel(const float* __restrict__ W, unsigned short* __restrict__ WTp) {
    int g = blockIdx.x * 256 + threadIdx.x;
    if (g >= 16 * 64 * 8 * 64) return;
    int l = g & 63, kc = (g >> 6) & 7, tile = (g >> 9) & 63, it = g >> 15;
    int n = tile * 16 + (l & 15);
    int m0 = kc * 32 + ((l >> 4) << 3);
    const float* Wi = W + (size_t)it * N_DIM * M_DIM;
    unsigned short h[8], m[8], lo[8];
#pragma unroll
    for (int j = 0; j < 8; ++j) split3(Wi[(size_t)n * M_DIM + m0 + j], h[j], m[j], lo[j]);
    size_t base = (((size_t)(it * 64 + tile) * 8 + kc) * 3) * 512 + l * 8;
#pragma unroll
    for (int j = 0; j < 8; ++j) {
        WTp[base + j] = h[j];
        WTp[base + 512 + j] = m[j];
        WTp[base + 1024 + j] = lo[j];
    }
}

// RP frag layout, panel-local: us = (((c*2+wm)*4+kc')*3 + p)*512 + l*8 + j
// value = r[wm*16 + (l&15)][ (c*4+kc')*32 + (l>>4)*8 + j ]
__global__ void prep_x_kernel(const float* __restrict__ x, unsigned short* __restrict__ RP) {
    int g = blockIdx.x * 256 + threadIdx.x;      // 512*2*2*4*64 = 524288
    if (g >= 524288) return;
    int l = g & 63, kcp = (g >> 6) & 3, wm = (g >> 8) & 1, c = (g >> 9) & 1, panel = g >> 10;
    int row = panel * 32 + wm * 16 + (l & 15);
    int k0 = c * 128 + kcp * 32 + ((l >> 4) << 3);
    unsigned short h[8], m[8], lo[8];
#pragma unroll
    for (int j = 0; j < 8; ++j) split3(x[(size_t)row * M_DIM + k0 + j], h[j], m[j], lo[j]);
    size_t base = (size_t)panel * RP_PANEL_US + ((((c * 2 + wm) * 4 + kcp) * 3)) * 512 + l * 8;
#pragma unroll
    for (int j = 0; j < 8; ++j) {
        RP[base + j] = h[j];
        RP[base + 512 + j] = m[j];
        RP[base + 1024 + j] = lo[j];
    }
}

// ================= SPP: select tau + apply shrink IN PLACE (UV: v -> u) =================
__global__ __launch_bounds__(1024)
void spp_kernel(float* __restrict__ UV, const float* __restrict__ thr_all,
                int iter, int kth) {
    const int l = threadIdx.x & 63;
    const int w = threadIdx.x >> 6;
    const int row = blockIdx.x * 16 + w;
    const float t = thr_all[iter];
    float* vp = UV + (size_t)row * N_DIM;
    float v[16]; unsigned key[16];
#pragma unroll
    for (int j = 0; j < 16; ++j) {
        v[j] = vp[l + 64 * j];
        key[j] = __float_as_uint(v[j]) & 0x7fffffffu;
    }
    unsigned p = 0;
#pragma unroll 1
    for (int b = 30; b >= 0; --b) {
        const unsigned cand = p | (1u << b);
        int cnt = 0;
#pragma unroll
        for (int j = 0; j < 16; ++j)
            cnt += __popcll(__ballot(key[j] >= cand));
        if (cnt >= kth) p = cand;       // uniform across lanes
    }
    const float thrv = fmaxf(t, __uint_as_float(p));
#pragma unroll
    for (int j = 0; j < 16; ++j)
        vp[l + 64 * j] = shrink_one(v[j], t, thrv);
}

#define LSTR2 136    // staging row stride (ushorts)
#define BUF16 6528   // one staging buffer = 3 planes * 16 rows * 136 us

// ================= G1: RP-half = frag(x - U * A^T)  (K = 1024) =================
// Round-15: 512 threads (8 waves), BM=16 -> LDS 26112 B -> 4 blocks/CU,
// 32 waves/CU, barriers sync only 8 waves. grid 1024 (16-row half-panels);
// each block writes its half of the 32-row RP panel (layout unchanged for g2).
// Per-wave work identical to r13 (32kc x 2tt x 6 MFMA); f64 drains per chunk.
__global__ __launch_bounds__(512)
void g1_kernel(const float* __restrict__ UV, const float* __restrict__ x,
               const unsigned short* __restrict__ ATp,
               unsigned short* __restrict__ RP) {
    __align__(16) __shared__ unsigned short smem[2 * BUF16];  // dbuf staging; epilogue img (12288us)
    const int tid = threadIdx.x;
    const int l = tid & 63, w = tid >> 6;       // 8 waves
    const int panel16 = blockIdx.x;
    const int row0 = panel16 * 16;
    const int arow = l & 15;
    const int akl  = (l >> 4) << 3;

    f32x4 acc_hi[2], acc_rest[2];
    double acc64[2][4];
#pragma unroll
    for (int t = 0; t < 2; ++t) {
        acc_hi[t] = (f32x4){0, 0, 0, 0};
        acc_rest[t] = (f32x4){0, 0, 0, 0};
#pragma unroll
        for (int e = 0; e < 4; ++e) acc64[t][e] = 0.0;
    }

    // ---- staging prologue: ch0 -> buf0; issue ch1 loads ----
    f32x2 st[2];
#pragma unroll
    for (int jj = 0; jj < 2; ++jj) {
        const int idx = tid + 512 * jj;
        const int r = idx >> 6, kq = idx & 63;
        st[jj] = *(const f32x2*)&UV[(size_t)(row0 + r) * N_DIM + kq * 2];
    }
#pragma unroll
    for (int jj = 0; jj < 2; ++jj) {
        const int idx = tid + 512 * jj;
        const int r = idx >> 6, kq = idx & 63;
        unsigned short h0, m0, lo0, h1, m1, lo1;
        split3(st[jj].x, h0, m0, lo0);
        split3(st[jj].y, h1, m1, lo1);
        const unsigned off = (unsigned)r * LSTR2 + kq * 2;
        *(unsigned*)&smem[off] = (unsigned)h0 | ((unsigned)h1 << 16);
        *(unsigned*)&smem[2176 + off] = (unsigned)m0 | ((unsigned)m1 << 16);
        *(unsigned*)&smem[4352 + off] = (unsigned)lo0 | ((unsigned)lo1 << 16);
    }
#pragma unroll
    for (int jj = 0; jj < 2; ++jj) {
        const int idx = tid + 512 * jj;
        const int r = idx >> 6, kq = idx & 63;
        st[jj] = *(const f32x2*)&UV[(size_t)(row0 + r) * N_DIM + 128 + kq * 2];
    }
    __syncthreads();

    // ---- main loop: ONE barrier per 128-k chunk; staging of c+1 overlaps MFMA of c ----
    for (int c = 0; c < 8; ++c) {
        const unsigned bb = (unsigned)(c & 1) * BUF16;
        const unsigned nb = (unsigned)((c + 1) & 1) * BUF16;
        if (c < 7) {
#pragma unroll
            for (int jj = 0; jj < 2; ++jj) {
                const int idx = tid + 512 * jj;
                const int r = idx >> 6, kq = idx & 63;
                unsigned short h0, m0, lo0, h1, m1, lo1;
                split3(st[jj].x, h0, m0, lo0);
                split3(st[jj].y, h1, m1, lo1);
                const unsigned off = (unsigned)r * LSTR2 + kq * 2;
                *(unsigned*)&smem[nb + off] = (unsigned)h0 | ((unsigned)h1 << 16);
                *(unsigned*)&smem[nb + 2176 + off] = (unsigned)m0 | ((unsigned)m1 << 16);
                *(unsigned*)&smem[nb + 4352 + off] = (unsigned)lo0 | ((unsigned)lo1 << 16);
            }
        }
        if (c < 6) {
#pragma unroll
            for (int jj = 0; jj < 2; ++jj) {
                const int idx = tid + 512 * jj;
                const int r = idx >> 6, kq = idx & 63;
                st[jj] = *(const f32x2*)&UV[(size_t)(row0 + r) * N_DIM + (c + 2) * 128 + kq * 2];
            }
        }
#pragma unroll
        for (int kc = 0; kc < 4; ++kc) {
            const unsigned ao = bb + (unsigned)arow * LSTR2 + kc * 32 + akl;
            short8 ah = *(const short8*)&smem[ao];
            short8 am = *(const short8*)&smem[ao + 2176];
            short8 al = *(const short8*)&smem[ao + 4352];
#pragma unroll
            for (int tt = 0; tt < 2; ++tt) {
                const int tile = w * 2 + tt;
                const unsigned bo = ((unsigned)(tile * 32 + c * 4 + kc) * 3) * 512 + l * 8;
                short8 bh = *(const short8*)&ATp[bo];
                short8 bm = *(const short8*)&ATp[bo + 512];
                short8 bl = *(const short8*)&ATp[bo + 1024];
                acc_hi[tt] = MF(ah, bh, acc_hi[tt]);
                acc_rest[tt] = MF(ah, bm, acc_rest[tt]);
                acc_rest[tt] = MF(am, bh, acc_rest[tt]);
                acc_rest[tt] = MF(am, bm, acc_rest[tt]);
                acc_rest[tt] = MF(ah, bl, acc_rest[tt]);
                acc_rest[tt] = MF(al, bh, acc_rest[tt]);
            }
        }
#pragma unroll
        for (int tt = 0; tt < 2; ++tt) {    // drain once per 128-k chunk
#pragma unroll
            for (int e = 0; e < 4; ++e) acc64[tt][e] += (double)acc_hi[tt][e];
            acc_hi[tt] = (f32x4){0, 0, 0, 0};
        }
        __syncthreads();                    // one barrier per chunk
    }

    // ---- epilogue: r -> split3 -> half-panel frag image in LDS (12288 us) ----
    {
#pragma unroll
        for (int tt = 0; tt < 2; ++tt) {
            const int ki = (w * 2 + tt) * 16 + (l & 15);       // output col 0..255
            const unsigned c_  = (unsigned)ki >> 7;
            const unsigned kcp = ((unsigned)ki >> 5) & 3;
            const unsigned hi2 = ((unsigned)ki >> 3) & 3;
            const unsigned fbase = ((c_ * 4 + kcp) * 3) * 512;
#pragma unroll
            for (int e = 0; e < 4; ++e) {
                const int mi = ((l >> 4) << 2) + e;            // row local 0..15
                const int row = row0 + mi;
                const double tot = acc64[tt][e] + (double)acc_rest[tt][e];
                const float rv = (float)((double)x[(size_t)row * M_DIM + ki] - tot);
                unsigned short h, m, lo;
                split3(rv, h, m, lo);
                const unsigned sl = fbase + (unsigned)(hi2 * 16 + mi) * 8 + (ki & 7);
                smem[sl] = h;
                smem[sl + 512] = m;
                smem[sl + 1024] = lo;
            }
        }
    }
    __syncthreads();
    {
        // dump half-panel (12288 us = 1536 uint4) into the 32-row RP panel:
        // local c_ block [c_*6144, +6144) -> RP + panel32*24576 + (c_*2+wm)*6144
        const int wm = panel16 & 1;
        const int panel32 = panel16 >> 1;
        const uint4* s4 = (const uint4*)smem;
#pragma unroll
        for (int qq = 0; qq < 3; ++qq) {
            const int q = tid + 512 * qq;            // 0..1535
            const int c_ = (q >= 768) ? 1 : 0;
            const int off = q - c_ * 768;
            uint4* d4 = (uint4*)(RP + (size_t)panel32 * RP_PANEL_US +
                                 (size_t)(c_ * 2 + wm) * 6144);
            d4[off] = s4[q];
        }
    }
}

// ================= G2: UV = U + r * W_i^T  (K = 256) =================
// r13 verbatim: BM=32, grid 2048 (512 panels x 4 cg). RP panel copied to LDS,
// ONE barrier, then barrier-free MFMA stream (B-frags from L2).
__global__ __launch_bounds__(1024)
void g2_kernel(const unsigned short* __restrict__ RP, const unsigned short* __restrict__ WTpi,
               float* UV, int iter) {
    __align__(16) __shared__ unsigned short img[24576];
    const int tid = threadIdx.x;
    const int l = tid & 63, w = tid >> 6;
    const int wm = w >> 3, wn = w & 7;
    const int panel = blockIdx.x >> 2, cg = blockIdx.x & 3;
    const int row0 = panel * 32;

    {   // copy 48KB RP panel -> LDS (pure copy)
        const uint4* s4 = (const uint4*)(RP + (size_t)panel * RP_PANEL_US);
        uint4* d4 = (uint4*)img;
        d4[tid] = s4[tid];
        d4[tid + 1024] = s4[tid + 1024];
        d4[tid + 2048] = s4[tid + 2048];
    }
    __syncthreads();

    f32x4 hi[2], rest[2], sum[2];
#pragma unroll
    for (int t = 0; t < 2; ++t) {
        hi[t] = (f32x4){0, 0, 0, 0};
        rest[t] = (f32x4){0, 0, 0, 0};
        sum[t] = (f32x4){0, 0, 0, 0};
    }

    for (int kc = 0; kc < 8; ++kc) {
        const unsigned ab = ((((unsigned)(kc >> 2) * 2 + wm) * 4 + (kc & 3)) * 3) * 512 + l * 8;
        short8 ah = *(const short8*)&img[ab];
        short8 am = *(const short8*)&img[ab + 512];
        short8 al = *(const short8*)&img[ab + 1024];
#pragma unroll
        for (int tt = 0; tt < 2; ++tt) {
            const int tile = cg * 16 + wn * 2 + tt;
            const unsigned bo = ((unsigned)(tile * 8 + kc) * 3) * 512 + l * 8;
            short8 bh = *(const short8*)&WTpi[bo];
            short8 bm = *(const short8*)&WTpi[bo + 512];
            short8 bl = *(const short8*)&WTpi[bo + 1024];
            hi[tt] = MF(ah, bh, hi[tt]);
            rest[tt] = MF(ah, bm, rest[tt]);
            rest[tt] = MF(am, bh, rest[tt]);
            rest[tt] = MF(am, bm, rest[tt]);
            rest[tt] = MF(ah, bl, rest[tt]);
            rest[tt] = MF(al, bh, rest[tt]);
        }
        if ((kc & 3) == 3) {
#pragma unroll
            for (int tt = 0; tt < 2; ++tt) {
#pragma unroll
                for (int e = 0; e < 4; ++e) sum[tt][e] += hi[tt][e];
                hi[tt] = (f32x4){0, 0, 0, 0};
            }
        }
    }

#pragma unroll
    for (int tt = 0; tt < 2; ++tt) {
        const int col = cg * 256 + wn * 32 + tt * 16 + (l & 15);
#pragma unroll
        for (int e = 0; e < 4; ++e) {
            const int row = row0 + wm * 16 + ((l >> 4) << 2) + e;
            const float tot = sum[tt][e] + rest[tt][e];
            const float us = (iter > 0) ? UV[(size_t)row * N_DIM + col] : 0.0f;
            UV[(size_t)row * N_DIM + col] = us + tot;
        }
    }
}

// ================= final: full select + shrink, in place =================
__global__ __launch_bounds__(256)
void s_kernel(float* UV, const float* __restrict__ thr_all, int iter, int kth) {
    __shared__ float v_s[8][1024];
    __shared__ float tau_s[8];
    const int tid = threadIdx.x;
    const int lane = tid & 63;
    const int wave = tid >> 6;
    const int row0 = blockIdx.x * 8;
    const float t = thr_all[iter];
    {
        const float4* Vg4 = (const float4*)(UV + (size_t)row0 * N_DIM);
        float4* vs4 = (float4*)(&v_s[0][0]);
#pragma unroll
        for (int c = 0; c < 8; ++c) vs4[tid + 256 * c] = Vg4[tid + 256 * c];
    }
    __syncthreads();
#pragma unroll 1
    for (int rr = 0; rr < 2; ++rr) {
        const int row = wave + rr * 4;
        unsigned key[16];
#pragma unroll
        for (int j = 0; j < 16; ++j)
            key[j] = __float_as_uint(v_s[row][lane + 64 * j]) & 0x7fffffffu;
        unsigned p = 0;
#pragma unroll 1
        for (int b = 30; b >= 0; --b) {
            const unsigned cand = p | (1u << b);
            int cnt = 0;
#pragma unroll
            for (int j = 0; j < 16; ++j) cnt += (key[j] >= cand) ? 1 : 0;
#pragma unroll
            for (int off = 32; off; off >>= 1) cnt += __shfl_xor(cnt, off);
            if (cnt >= kth) p = cand;
        }
        if (lane == 0) tau_s[row] = __uint_as_float(p);
    }
    __syncthreads();
    {
        const float4* vs4 = (const float4*)&v_s[0][0];
        float4* Uw = (float4*)(UV + (size_t)row0 * N_DIM);
#pragma unroll 1
        for (int c = 0; c < 8; ++c) {
            const int idx = tid + 256 * c;
            const int row = idx >> 8;
            const float thrv = fmaxf(t, tau_s[row]);
            float4 v = vs4[idx];
            float4 o;
            o.x = shrink_one(v.x, t, thrv);
            o.y = shrink_one(v.y, t, thrv);
            o.z = shrink_one(v.z, t, thrv);
            o.w = shrink_one(v.w, t, thrv);
            Uw[idx] = o;
        }
    }
}

// ===================== round-3 fallback kernels ======================
#define DFMA4(acc, s, v) do { \
    (acc).x += (double)(s) * (double)(v).x; \
    (acc).y += (double)(s) * (double)(v).y; \
    (acc).z += (double)(s) * (double)(v).z; \
    (acc).w += (double)(s) * (double)(v).w; } while (0)

__global__ void transpose_kernel(const float* __restrict__ in, float* __restrict__ out,
                                 int R, int C) {
    __shared__ float tile[32][33];
    int s = blockIdx.z;
    const float* ip = in + (size_t)s * R * C;
    float* op = out + (size_t)s * R * C;
    int c0 = blockIdx.x * 32, r0 = blockIdx.y * 32;
    int tx = threadIdx.x, ty = threadIdx.y;
#pragma unroll
    for (int k = 0; k < 4; ++k)
        tile[ty + 8 * k][tx] = ip[(size_t)(r0 + ty + 8 * k) * C + (c0 + tx)];
    __syncthreads();
#pragma unroll
    for (int k = 0; k < 4; ++k)
        op[(size_t)(c0 + ty + 8 * k) * R + (r0 + tx)] = tile[tx][ty + 8 * k];
}

__global__ void zero_kernel(float* __restrict__ p, int n) {
    int i = blockIdx.x * blockDim.x + threadIdx.x;
    int stride = gridDim.x * blockDim.x;
    for (; i < n; i += stride) p[i] = 0.0f;
}

template <bool T>
__device__ __forceinline__ float4 loadAT(const float* __restrict__ p, int n, int m4) {
    if constexpr (T) {
        return ((const float4*)p)[n * 64 + m4];
    } else {
        float4 r;
        r.x = p[(size_t)(4 * m4 + 0) * N_DIM + n];
        r.y = p[(size_t)(4 * m4 + 1) * N_DIM + n];
        r.z = p[(size_t)(4 * m4 + 2) * N_DIM + n];
        r.w = p[(size_t)(4 * m4 + 3) * N_DIM + n];
        return r;
    }
}
template <bool T>
__device__ __forceinline__ float4 loadWT(const float* __restrict__ p, int m, int n4) {
    if constexpr (T) {
        return ((const float4*)p)[m * 256 + n4];
    } else {
        float4 r;
        r.x = p[(size_t)(4 * n4 + 0) * M_DIM + m];
        r.y = p[(size_t)(4 * n4 + 1) * M_DIM + m];
        r.z = p[(size_t)(4 * n4 + 2) * M_DIM + m];
        r.w = p[(size_t)(4 * n4 + 3) * M_DIM + m];
        return r;
    }
}

template <bool T>
__global__ __launch_bounds__(256)
void lista_iter_kernel(const float* __restrict__ x, const float* __restrict__ Ap,
                       const float* __restrict__ Wp, const float* __restrict__ thr_all,
                       float* __restrict__ U, int iter, int kth) {
    __shared__ float u_s[8][1024];
    __shared__ float r_s[8][256];
    __shared__ float tau_s[8];
    const int tid = threadIdx.x;
    const int lane = tid & 63;
    const int wave = tid >> 6;
    const int row0 = blockIdx.x * 8;
    const float t = thr_all[iter];
    {
        const float4* Ug4 = (const float4*)(U + (size_t)row0 * N_DIM);
        float4* us4 = (float4*)(&u_s[0][0]);
#pragma unroll
        for (int c = 0; c < 8; ++c) us4[tid + 256 * c] = Ug4[tid + 256 * c];
    }
    __syncthreads();
    {
        double4 acc0 = {0, 0, 0, 0}, acc1 = {0, 0, 0, 0};
        const float4* u0p = (const float4*)&u_s[wave][0];
        const float4* u1p = (const float4*)&u_s[wave + 4][0];
        for (int n4 = 0; n4 < 256; ++n4) {
            float4 u0 = u0p[n4];
            float4 u1 = u1p[n4];
            float4 a0 = loadAT<T>(Ap, 4 * n4 + 0, lane);
            float4 a1 = loadAT<T>(Ap, 4 * n4 + 1, lane);
            float4 a2 = loadAT<T>(Ap, 4 * n4 + 2, lane);
            float4 a3 = loadAT<T>(Ap, 4 * n4 + 3, lane);
            DFMA4(acc0, u0.x, a0); DFMA4(acc0, u0.y, a1); DFMA4(acc0, u0.z, a2); DFMA4(acc0, u0.w, a3);
            DFMA4(acc1, u1.x, a0); DFMA4(acc1, u1.y, a1); DFMA4(acc1, u1.z, a2); DFMA4(acc1, u1.w, a3);
        }
        float4 xv0 = ((const float4*)(x + (size_t)(row0 + wave) * M_DIM))[lane];
        float4 xv1 = ((const float4*)(x + (size_t)(row0 + wave + 4) * M_DIM))[lane];
        float4 rv0, rv1;
        rv0.x = (float)((double)xv0.x - acc0.x);
        rv0.y = (float)((double)xv0.y - acc0.y);
        rv0.z = (float)((double)xv0.z - acc0.z);
        rv0.w = (float)((double)xv0.w - acc0.w);
        rv1.x = (float)((double)xv1.x - acc1.x);
        rv1.y = (float)((double)xv1.y - acc1.y);
        rv1.z = (float)((double)xv1.z - acc1.z);
        rv1.w = (float)((double)xv1.w - acc1.w);
        ((float4*)&r_s[wave][0])[lane] = rv0;
        ((float4*)&r_s[wave + 4][0])[lane] = rv1;
    }
    __syncthreads();
    {
        const float4* r0p = (const float4*)&r_s[wave][0];
        const float4* r1p = (const float4*)&r_s[wave + 4][0];
        float4* u0p = (float4*)&u_s[wave][0];
        float4* u1p = (float4*)&u_s[wave + 4][0];
#pragma unroll 1
        for (int q = 0; q < 4; ++q) {
            const int n4 = lane + 64 * q;
            double4 acc0 = {0, 0, 0, 0}, acc1 = {0, 0, 0, 0};
            for (int m4 = 0; m4 < 64; ++m4) {
                float4 r0 = r0p[m4];
                float4 r1 = r1p[m4];
                float4 w0 = loadWT<T>(Wp, 4 * m4 + 0, n4);
                float4 w1 = loadWT<T>(Wp, 4 * m4 + 1, n4);
                float4 w2 = loadWT<T>(Wp, 4 * m4 + 2, n4);
                float4 w3 = loadWT<T>(Wp, 4 * m4 + 3, n4);
                DFMA4(acc0, r0.x, w0); DFMA4(acc0, r0.y, w1); DFMA4(acc0, r0.z, w2); DFMA4(acc0, r0.w, w3);
                DFMA4(acc1, r1.x, w0); DFMA4(acc1, r1.y, w1); DFMA4(acc1, r1.z, w2); DFMA4(acc1, r1.w, w3);
            }
            float4 uv0 = u0p[n4];
            uv0.x = (float)((double)uv0.x + acc0.x);
            uv0.y = (float)((double)uv0.y + acc0.y);
            uv0.z = (float)((double)uv0.z + acc0.z);
            uv0.w = (float)((double)uv0.w + acc0.w);
            u0p[n4] = uv0;
            float4 uv1 = u1p[n4];
            uv1.x = (float)((double)uv1.x + acc1.x);
            uv1.y = (float)((double)uv1.y + acc1.y);
            uv1.z = (float)((double)uv1.z + acc1.z);
            uv1.w = (float)((double)uv1.w + acc1.w);
            u1p[n4] = uv1;
        }
    }
    __syncthreads();
    {
#pragma unroll 1
        for (int rr = 0; rr < 2; ++rr) {
            const int row = wave + rr * 4;
            unsigned key[16];
#pragma unroll
            for (int j = 0; j < 16; ++j)
                key[j] = __float_as_uint(u_s[row][lane + 64 * j]) & 0x7fffffffu;
            unsigned p = 0;
#pragma unroll 1
            for (int b = 30; b >= 0; --b) {
                const unsigned cand = p | (1u << b);
                int cnt = 0;
#pragma unroll
                for (int j = 0; j < 16; ++j) cnt += (key[j] >= cand) ? 1 : 0;
#pragma unroll
                for (int off = 32; off; off >>= 1) cnt += __shfl_xor(cnt, off);
                if (cnt >= kth) p = cand;
            }
            if (lane == 0) tau_s[row] = __uint_as_float(p);
        }
    }
    __syncthreads();
    {
        const float4* us4 = (const float4*)&u_s[0][0];
        float4* Uw = (float4*)(U + (size_t)row0 * N_DIM);
#pragma unroll 1
        for (int c = 0; c < 8; ++c) {
            const int idx = tid + 256 * c;
            const int row = idx >> 8;
            const float thrv = fmaxf(t, tau_s[row]);
            float4 v = us4[idx];
            float4 o;
            o.x = shrink_one(v.x, t, thrv);
            o.y = shrink_one(v.y, t, thrv);
            o.z = shrink_one(v.z, t, thrv);
            o.w = shrink_one(v.w, t, thrv);
            Uw[idx] = o;
        }
    }
}

// ================= launcher =================
extern "C" void kernel_launch(void* const* d_in, const int* in_sizes, int n_in,
                              void* d_out, int out_size, void* d_ws, size_t ws_size,
                              hipStream_t stream) {
    const float* x   = (const float*)d_in[0];  // [16384][256]
    const float* A   = (const float*)d_in[1];  // [256][1024]
    const float* W   = (const float*)d_in[2];  // [16][1024][256]
    const float* thr = (const float*)d_in[3];  // [16]

    float* UV = (float*)d_out;                 // v (pre-shrink) / u (post-spp) state

    static const int ktab[DEPTH] = {13, 25, 37, 50, 52, 52, 52, 52,
                                    52, 52, 52, 52, 52, 52, 52, 52};

    if (ws_size >= WS_FAST_NEED) {
        unsigned short* ATp = (unsigned short*)((char*)d_ws + ATP_OFF_B);
        unsigned short* WTp = (unsigned short*)((char*)d_ws + WTP_OFF_B);
        unsigned short* RP  = (unsigned short*)((char*)d_ws + RP_OFF_B);

        prep_a_kernel<<<128, 256, 0, stream>>>(A, ATp);
        prep_w_kernel<<<2048, 256, 0, stream>>>(W, WTp);
        prep_x_kernel<<<2048, 256, 0, stream>>>(x, RP);

        // iter 0: u=0, r=x (RP already holds frag(x))
        g2_kernel<<<2048, 1024, 0, stream>>>(RP, WTp, UV, 0);   // UV = v_0

        for (int it = 1; it < DEPTH; ++it) {
            // UV: v_{it-1} -> u_{it-1} (select + shrink in place)
            spp_kernel<<<B_ROWS / 16, 1024, 0, stream>>>(UV, thr, it - 1, ktab[it - 1]);
            // RP = frag(x - u * A^T)   (16-row half-panels, 4 blocks/CU)
            g1_kernel<<<B_ROWS / 16, 512, 0, stream>>>(UV, x, ATp, RP);
            // UV = u + r * W^T = v_it
            g2_kernel<<<2048, 1024, 0, stream>>>(RP, WTp + (size_t)it * WTP_SLICE, UV, it);
        }
        s_kernel<<<B_ROWS / 8, 256, 0, stream>>>(UV, thr, DEPTH - 1, ktab[DEPTH - 1]);
    } else if (ws_size >= WS_OLD_NEED) {
        float* ws = (float*)d_ws;
        float* AT = ws + AT_OFF;
        float* WT = ws + WT_OFF;
        zero_kernel<<<1024, 256, 0, stream>>>(UV, B_ROWS * N_DIM);
        dim3 tb(32, 8);
        transpose_kernel<<<dim3(N_DIM / 32, M_DIM / 32, 1), tb, 0, stream>>>(A, AT, M_DIM, N_DIM);
        transpose_kernel<<<dim3(M_DIM / 32, N_DIM / 32, DEPTH), tb, 0, stream>>>(W, WT, N_DIM, M_DIM);
        for (int it = 0; it < DEPTH; ++it)
            lista_iter_kernel<true><<<B_ROWS / 8, 256, 0, stream>>>(
                x, AT, WT + (size_t)it * M_DIM * N_DIM, thr, UV, it, ktab[it]);
    } else {
        zero_kernel<<<1024, 256, 0, stream>>>(UV, B_ROWS * N_DIM);
        for (int it = 0; it < DEPTH; ++it)
            lista_iter_kernel<false><<<B_ROWS / 8, 256, 0, stream>>>(
                x, A, W + (size_t)it * N_DIM * M_DIM, thr, UV, it, ktab[it]);
    }
}

// Round 16
// 3152.344 us; speedup vs baseline: 1.2819x; 1.0091x over previous
//
#include <hip/hip_runtime.h>
#include <hip/hip_bf16.h>

#define B_ROWS 16384
#define M_DIM  256
#define N_DIM  1024
#define DEPTH  16

typedef __attribute__((ext_vector_type(8))) short short8;
typedef __attribute__((ext_vector_type(4))) float f32x4;
typedef __attribute__((ext_vector_type(2))) float f32x2;

// ---------------- fast path ws layout (bytes) ----------------
#define ATP_OFF_B   0
#define WTP_OFF_B   1572864
#define RP_OFF_B    (1572864 + 25165824)
#define WS_FAST_NEED ((size_t)RP_OFF_B + 25165824)
#define WTP_SLICE   (64 * 8 * 3 * 512)              // ushorts per iteration
#define RP_PANEL_US 24576                            // ushorts per 32-row panel (48KB)

// ---------------- fallback (round-3) ws layout ----------------
#define AT_OFF 0
#define WT_OFF (262144)
#define WS_OLD_NEED ((size_t)(262144 + 16 * 262144) * 4)

// ================= helpers =================
__device__ __forceinline__ unsigned short bf16r(float f) {
    unsigned u = __float_as_uint(f);
    u += 0x7fffu + ((u >> 16) & 1u);
    return (unsigned short)(u >> 16);
}
__device__ __forceinline__ float bf2f(unsigned short h) {
    return __uint_as_float(((unsigned)h) << 16);
}
__device__ __forceinline__ void split3(float x, unsigned short& h, unsigned short& m,
                                       unsigned short& lo) {
    h = bf16r(x); float r1 = x - bf2f(h);
    m = bf16r(r1); float r2 = r1 - bf2f(m);
    lo = bf16r(r2);
}
__device__ __forceinline__ f32x4 MF(short8 a, short8 b, f32x4 c) {
    return __builtin_amdgcn_mfma_f32_16x16x32_bf16(a, b, c, 0, 0, 0);
}
__device__ __forceinline__ float shrink_one(float v, float t, float thrv) {
    float a = fabsf(v);
    return (a >= thrv) ? v : copysignf(fmaxf(a - t, 0.0f), v);
}

// ================= prep kernels (frag-ordered bf16 planes) =================
__global__ void prep_a_kernel(const float* __restrict__ A, unsigned short* __restrict__ ATp) {
    int g = blockIdx.x * 256 + threadIdx.x;
    if (g >= 16 * 32 * 64) return;
    int l = g & 63, kc = (g >> 6) & 31, tile = g >> 11;
    int row = tile * 16 + (l & 15);
    int k0 = kc * 32 + ((l >> 4) << 3);
    unsigned short h[8], m[8], lo[8];
#pragma unroll
    for (int j = 0; j < 8; ++j) split3(A[(size_t)row * N_DIM + k0 + j], h[j], m[j], lo[j]);
    size_t base = ((size_t)(tile * 32 + kc) * 3) * 512 + l * 8;
#pragma unroll
    for (int j = 0; j < 8; ++j) {
        ATp[base + j] = h[j];
        ATp[base + 512 + j] = m[j];
        ATp[base + 1024 + j] = lo[j];
    }
}

__global__ void prep_w_kernel(const float* __restrict__ W, unsigned short* __restrict__ WTp) {
    int g = blockIdx.x * 256 + threadIdx.x;
    if (g >= 16 * 64 * 8 * 64) return;
    int l = g & 63, kc = (g >> 6) & 7, tile = (g >> 9) & 63, it = g >> 15;
    int n = tile * 16 + (l & 15);
    int m0 = kc * 32 + ((l >> 4) << 3);
    const float* Wi = W + (size_t)it * N_DIM * M_DIM;
    unsigned short h[8], m[8], lo[8];
#pragma unroll
    for (int j = 0; j < 8; ++j) split3(Wi[(size_t)n * M_DIM + m0 + j], h[j], m[j], lo[j]);
    size_t base = (((size_t)(it * 64 + tile) * 8 + kc) * 3) * 512 + l * 8;
#pragma unroll
    for (int j = 0; j < 8; ++j) {
        WTp[base + j] = h[j];
        WTp[base + 512 + j] = m[j];
        WTp[base + 1024 + j] = lo[j];
    }
}

// RP frag layout, panel-local: us = (((c*2+wm)*4+kc')*3 + p)*512 + l*8 + j
// value = r[wm*16 + (l&15)][ (c*4+kc')*32 + (l>>4)*8 + j ]
__global__ void prep_x_kernel(const float* __restrict__ x, unsigned short* __restrict__ RP) {
    int g = blockIdx.x * 256 + threadIdx.x;      // 512*2*2*4*64 = 524288
    if (g >= 524288) return;
    int l = g & 63, kcp = (g >> 6) & 3, wm = (g >> 8) & 1, c = (g >> 9) & 1, panel = g >> 10;
    int row = panel * 32 + wm * 16 + (l & 15);
    int k0 = c * 128 + kcp * 32 + ((l >> 4) << 3);
    unsigned short h[8], m[8], lo[8];
#pragma unroll
    for (int j = 0; j < 8; ++j) split3(x[(size_t)row * M_DIM + k0 + j], h[j], m[j], lo[j]);
    size_t base = (size_t)panel * RP_PANEL_US + ((((c * 2 + wm) * 4 + kcp) * 3)) * 512 + l * 8;
#pragma unroll
    for (int j = 0; j < 8; ++j) {
        RP[base + j] = h[j];
        RP[base + 512 + j] = m[j];
        RP[base + 1024 + j] = lo[j];
    }
}

// ================= SPP: select tau + apply shrink IN PLACE (UV: v -> u) =================
__global__ __launch_bounds__(1024)
void spp_kernel(float* __restrict__ UV, const float* __restrict__ thr_all,
                int iter, int kth) {
    const int l = threadIdx.x & 63;
    const int w = threadIdx.x >> 6;
    const int row = blockIdx.x * 16 + w;
    const float t = thr_all[iter];
    float* vp = UV + (size_t)row * N_DIM;
    float v[16]; unsigned key[16];
#pragma unroll
    for (int j = 0; j < 16; ++j) {
        v[j] = vp[l + 64 * j];
        key[j] = __float_as_uint(v[j]) & 0x7fffffffu;
    }
    unsigned p = 0;
#pragma unroll 1
    for (int b = 30; b >= 0; --b) {
        const unsigned cand = p | (1u << b);
        int cnt = 0;
#pragma unroll
        for (int j = 0; j < 16; ++j)
            cnt += __popcll(__ballot(key[j] >= cand));
        if (cnt >= kth) p = cand;       // uniform across lanes
    }
    const float thrv = fmaxf(t, __uint_as_float(p));
#pragma unroll
    for (int j = 0; j < 16; ++j)
        vp[l + 64 * j] = shrink_one(v[j], t, thrv);
}

#define LSTR2 136    // staging row stride (ushorts)
#define BUFUS 13056  // one staging buffer = 3 planes * 32 rows * 136 us

// ================= G1: RP = frag(x - U * A^T)  (K = 1024) =================
// r13 exact geometry (grid 512, 1024 thr, 16 waves 2wm x 8wn, tt=2, BM=32,
// f64 drains, dbuf staging, one barrier per 128-k chunk) + T5 setprio around
// the MFMA cluster (blocks are independent -> wave role diversity exists).
__global__ __launch_bounds__(1024)
void g1_kernel(const float* __restrict__ UV, const float* __restrict__ x,
               const unsigned short* __restrict__ ATp,
               unsigned short* __restrict__ RP) {
    __align__(16) __shared__ unsigned short smem[2 * BUFUS];  // dbuf staging; epilogue img
    const int tid = threadIdx.x;
    const int l = tid & 63, w = tid >> 6;
    const int wm = w >> 3, wn = w & 7;
    const int panel = blockIdx.x;
    const int row0 = panel * 32;
    const int arow = 16 * wm + (l & 15);
    const int akl  = (l >> 4) << 3;

    f32x4 acc_hi[2], acc_rest[2];
    double acc64[2][4];
#pragma unroll
    for (int t = 0; t < 2; ++t) {
        acc_hi[t] = (f32x4){0, 0, 0, 0};
        acc_rest[t] = (f32x4){0, 0, 0, 0};
#pragma unroll
        for (int e = 0; e < 4; ++e) acc64[t][e] = 0.0;
    }

    // ---- staging prologue: ch0 -> buf0; issue ch1 loads ----
    f32x2 st[2];
#pragma unroll
    for (int jj = 0; jj < 2; ++jj) {
        const int idx = tid + 1024 * jj;
        const int r = idx >> 6, kq = idx & 63;
        st[jj] = *(const f32x2*)&UV[(size_t)(row0 + r) * N_DIM + kq * 2];
    }
#pragma unroll
    for (int jj = 0; jj < 2; ++jj) {
        const int idx = tid + 1024 * jj;
        const int r = idx >> 6, kq = idx & 63;
        unsigned short h0, m0, lo0, h1, m1, lo1;
        split3(st[jj].x, h0, m0, lo0);
        split3(st[jj].y, h1, m1, lo1);
        const unsigned off = (unsigned)r * LSTR2 + kq * 2;
        *(unsigned*)&smem[off] = (unsigned)h0 | ((unsigned)h1 << 16);
        *(unsigned*)&smem[4352 + off] = (unsigned)m0 | ((unsigned)m1 << 16);
        *(unsigned*)&smem[8704 + off] = (unsigned)lo0 | ((unsigned)lo1 << 16);
    }
#pragma unroll
    for (int jj = 0; jj < 2; ++jj) {
        const int idx = tid + 1024 * jj;
        const int r = idx >> 6, kq = idx & 63;
        st[jj] = *(const f32x2*)&UV[(size_t)(row0 + r) * N_DIM + 128 + kq * 2];
    }
    __syncthreads();

    // ---- main loop: ONE barrier per chunk; staging of c+1 overlaps MFMA of c ----
    for (int c = 0; c < 8; ++c) {
        const unsigned bb = (unsigned)(c & 1) * BUFUS;
        const unsigned nb = (unsigned)((c + 1) & 1) * BUFUS;
        if (c < 7) {
#pragma unroll
            for (int jj = 0; jj < 2; ++jj) {
                const int idx = tid + 1024 * jj;
                const int r = idx >> 6, kq = idx & 63;
                unsigned short h0, m0, lo0, h1, m1, lo1;
                split3(st[jj].x, h0, m0, lo0);
                split3(st[jj].y, h1, m1, lo1);
                const unsigned off = (unsigned)r * LSTR2 + kq * 2;
                *(unsigned*)&smem[nb + off] = (unsigned)h0 | ((unsigned)h1 << 16);
                *(unsigned*)&smem[nb + 4352 + off] = (unsigned)m0 | ((unsigned)m1 << 16);
                *(unsigned*)&smem[nb + 8704 + off] = (unsigned)lo0 | ((unsigned)lo1 << 16);
            }
        }
        if (c < 6) {
#pragma unroll
            for (int jj = 0; jj < 2; ++jj) {
                const int idx = tid + 1024 * jj;
                const int r = idx >> 6, kq = idx & 63;
                st[jj] = *(const f32x2*)&UV[(size_t)(row0 + r) * N_DIM + (c + 2) * 128 + kq * 2];
            }
        }
        __builtin_amdgcn_s_setprio(1);          // T5: favor MFMA-issuing waves
#pragma unroll
        for (int kc = 0; kc < 4; ++kc) {
            const unsigned ao = bb + (unsigned)arow * LSTR2 + kc * 32 + akl;
            short8 ah = *(const short8*)&smem[ao];
            short8 am = *(const short8*)&smem[ao + 4352];
            short8 al = *(const short8*)&smem[ao + 8704];
#pragma unroll
            for (int tt = 0; tt < 2; ++tt) {
                const int tile = wn * 2 + tt;
                const unsigned bo = ((unsigned)(tile * 32 + c * 4 + kc) * 3) * 512 + l * 8;
                short8 bh = *(const short8*)&ATp[bo];
                short8 bm = *(const short8*)&ATp[bo + 512];
                short8 bl = *(const short8*)&ATp[bo + 1024];
                acc_hi[tt] = MF(ah, bh, acc_hi[tt]);
                acc_rest[tt] = MF(ah, bm, acc_rest[tt]);
                acc_rest[tt] = MF(am, bh, acc_rest[tt]);
                acc_rest[tt] = MF(am, bm, acc_rest[tt]);
                acc_rest[tt] = MF(ah, bl, acc_rest[tt]);
                acc_rest[tt] = MF(al, bh, acc_rest[tt]);
            }
        }
        __builtin_amdgcn_s_setprio(0);
#pragma unroll
        for (int tt = 0; tt < 2; ++tt) {    // drain once per 128-k chunk
#pragma unroll
            for (int e = 0; e < 4; ++e) acc64[tt][e] += (double)acc_hi[tt][e];
            acc_hi[tt] = (f32x4){0, 0, 0, 0};
        }
        __syncthreads();                    // one barrier per chunk
    }

    // ---- epilogue: r -> split3 -> frag image in LDS -> linear dump to RP ----
    {
        const int cimg = wn >> 2, kcp = wn & 3;
        const unsigned fbase = ((((unsigned)(cimg * 2 + wm) * 4 + kcp) * 3)) * 512;
#pragma unroll
        for (int tt = 0; tt < 2; ++tt) {
            const int col = wn * 32 + tt * 16 + (l & 15);
            const int hi2 = (tt * 2 + ((l & 15) >> 3)) & 3;
#pragma unroll
            for (int e = 0; e < 4; ++e) {
                const int rl = ((l >> 4) << 2) + e;          // row_local & 15
                const int row = row0 + wm * 16 + rl;
                const double tot = acc64[tt][e] + (double)acc_rest[tt][e];
                const float rv = (float)((double)x[(size_t)row * M_DIM + col] - tot);
                unsigned short h, m, lo;
                split3(rv, h, m, lo);
                const unsigned sl = fbase + (unsigned)(hi2 * 16 + rl) * 8 + (l & 7);
                smem[sl] = h;
                smem[sl + 512] = m;
                smem[sl + 1024] = lo;
            }
        }
    }
    __syncthreads();
    {
        // panel image = 24576 us = 3072 uint4 = 3 x 1024
        const uint4* s4 = (const uint4*)smem;
        uint4* d4 = (uint4*)(RP + (size_t)panel * RP_PANEL_US);
        d4[tid] = s4[tid];
        d4[tid + 1024] = s4[tid + 1024];
        d4[tid + 2048] = s4[tid + 2048];
    }
}

// ================= G2: UV = U + r * W_i^T  (K = 256) =================
// r13 exact + T5 setprio around the barrier-free MFMA stream.
__global__ __launch_bounds__(1024)
void g2_kernel(const unsigned short* __restrict__ RP, const unsigned short* __restrict__ WTpi,
               float* UV, int iter) {
    __align__(16) __shared__ unsigned short img[24576];
    const int tid = threadIdx.x;
    const int l = tid & 63, w = tid >> 6;
    const int wm = w >> 3, wn = w & 7;
    const int panel = blockIdx.x >> 2, cg = blockIdx.x & 3;
    const int row0 = panel * 32;

    {   // copy 48KB RP panel -> LDS (pure copy)
        const uint4* s4 = (const uint4*)(RP + (size_t)panel * RP_PANEL_US);
        uint4* d4 = (uint4*)img;
        d4[tid] = s4[tid];
        d4[tid + 1024] = s4[tid + 1024];
        d4[tid + 2048] = s4[tid + 2048];
    }
    __syncthreads();

    f32x4 hi[2], rest[2], sum[2];
#pragma unroll
    for (int t = 0; t < 2; ++t) {
        hi[t] = (f32x4){0, 0, 0, 0};
        rest[t] = (f32x4){0, 0, 0, 0};
        sum[t] = (f32x4){0, 0, 0, 0};
    }

    __builtin_amdgcn_s_setprio(1);              // T5
    for (int kc = 0; kc < 8; ++kc) {
        const unsigned ab = ((((unsigned)(kc >> 2) * 2 + wm) * 4 + (kc & 3)) * 3) * 512 + l * 8;
        short8 ah = *(const short8*)&img[ab];
        short8 am = *(const short8*)&img[ab + 512];
        short8 al = *(const short8*)&img[ab + 1024];
#pragma unroll
        for (int tt = 0; tt < 2; ++tt) {
            const int tile = cg * 16 + wn * 2 + tt;
            const unsigned bo = ((unsigned)(tile * 8 + kc) * 3) * 512 + l * 8;
            short8 bh = *(const short8*)&WTpi[bo];
            short8 bm = *(const short8*)&WTpi[bo + 512];
            short8 bl = *(const short8*)&WTpi[bo + 1024];
            hi[tt] = MF(ah, bh, hi[tt]);
            rest[tt] = MF(ah, bm, rest[tt]);
            rest[tt] = MF(am, bh, rest[tt]);
            rest[tt] = MF(am, bm, rest[tt]);
            rest[tt] = MF(ah, bl, rest[tt]);
            rest[tt] = MF(al, bh, rest[tt]);
        }
        if ((kc & 3) == 3) {
#pragma unroll
            for (int tt = 0; tt < 2; ++tt) {
#pragma unroll
                for (int e = 0; e < 4; ++e) sum[tt][e] += hi[tt][e];
                hi[tt] = (f32x4){0, 0, 0, 0};
            }
        }
    }
    __builtin_amdgcn_s_setprio(0);

#pragma unroll
    for (int tt = 0; tt < 2; ++tt) {
        const int col = cg * 256 + wn * 32 + tt * 16 + (l & 15);
#pragma unroll
        for (int e = 0; e < 4; ++e) {
            const int row = row0 + wm * 16 + ((l >> 4) << 2) + e;
            const float tot = sum[tt][e] + rest[tt][e];
            const float us = (iter > 0) ? UV[(size_t)row * N_DIM + col] : 0.0f;
            UV[(size_t)row * N_DIM + col] = us + tot;
        }
    }
}

// ================= final: full select + shrink, in place =================
__global__ __launch_bounds__(256)
void s_kernel(float* UV, const float* __restrict__ thr_all, int iter, int kth) {
    __shared__ float v_s[8][1024];
    __shared__ float tau_s[8];
    const int tid = threadIdx.x;
    const int lane = tid & 63;
    const int wave = tid >> 6;
    const int row0 = blockIdx.x * 8;
    const float t = thr_all[iter];
    {
        const float4* Vg4 = (const float4*)(UV + (size_t)row0 * N_DIM);
        float4* vs4 = (float4*)(&v_s[0][0]);
#pragma unroll
        for (int c = 0; c < 8; ++c) vs4[tid + 256 * c] = Vg4[tid + 256 * c];
    }
    __syncthreads();
#pragma unroll 1
    for (int rr = 0; rr < 2; ++rr) {
        const int row = wave + rr * 4;
        unsigned key[16];
#pragma unroll
        for (int j = 0; j < 16; ++j)
            key[j] = __float_as_uint(v_s[row][lane + 64 * j]) & 0x7fffffffu;
        unsigned p = 0;
#pragma unroll 1
        for (int b = 30; b >= 0; --b) {
            const unsigned cand = p | (1u << b);
            int cnt = 0;
#pragma unroll
            for (int j = 0; j < 16; ++j) cnt += (key[j] >= cand) ? 1 : 0;
#pragma unroll
            for (int off = 32; off; off >>= 1) cnt += __shfl_xor(cnt, off);
            if (cnt >= kth) p = cand;
        }
        if (lane == 0) tau_s[row] = __uint_as_float(p);
    }
    __syncthreads();
    {
        const float4* vs4 = (const float4*)&v_s[0][0];
        float4* Uw = (float4*)(UV + (size_t)row0 * N_DIM);
#pragma unroll 1
        for (int c = 0; c < 8; ++c) {
            const int idx = tid + 256 * c;
            const int row = idx >> 8;
            const float thrv = fmaxf(t, tau_s[row]);
            float4 v = vs4[idx];
            float4 o;
            o.x = shrink_one(v.x, t, thrv);
            o.y = shrink_one(v.y, t, thrv);
            o.z = shrink_one(v.z, t, thrv);
            o.w = shrink_one(v.w, t, thrv);
            Uw[idx] = o;
        }
    }
}

// ===================== round-3 fallback kernels ======================
#define DFMA4(acc, s, v) do { \
    (acc).x += (double)(s) * (double)(v).x; \
    (acc).y += (double)(s) * (double)(v).y; \
    (acc).z += (double)(s) * (double)(v).z; \
    (acc).w += (double)(s) * (double)(v).w; } while (0)

__global__ void transpose_kernel(const float* __restrict__ in, float* __restrict__ out,
                                 int R, int C) {
    __shared__ float tile[32][33];
    int s = blockIdx.z;
    const float* ip = in + (size_t)s * R * C;
    float* op = out + (size_t)s * R * C;
    int c0 = blockIdx.x * 32, r0 = blockIdx.y * 32;
    int tx = threadIdx.x, ty = threadIdx.y;
#pragma unroll
    for (int k = 0; k < 4; ++k)
        tile[ty + 8 * k][tx] = ip[(size_t)(r0 + ty + 8 * k) * C + (c0 + tx)];
    __syncthreads();
#pragma unroll
    for (int k = 0; k < 4; ++k)
        op[(size_t)(c0 + ty + 8 * k) * R + (r0 + tx)] = tile[tx][ty + 8 * k];
}

__global__ void zero_kernel(float* __restrict__ p, int n) {
    int i = blockIdx.x * blockDim.x + threadIdx.x;
    int stride = gridDim.x * blockDim.x;
    for (; i < n; i += stride) p[i] = 0.0f;
}

template <bool T>
__device__ __forceinline__ float4 loadAT(const float* __restrict__ p, int n, int m4) {
    if constexpr (T) {
        return ((const float4*)p)[n * 64 + m4];
    } else {
        float4 r;
        r.x = p[(size_t)(4 * m4 + 0) * N_DIM + n];
        r.y = p[(size_t)(4 * m4 + 1) * N_DIM + n];
        r.z = p[(size_t)(4 * m4 + 2) * N_DIM + n];
        r.w = p[(size_t)(4 * m4 + 3) * N_DIM + n];
        return r;
    }
}
template <bool T>
__device__ __forceinline__ float4 loadWT(const float* __restrict__ p, int m, int n4) {
    if constexpr (T) {
        return ((const float4*)p)[m * 256 + n4];
    } else {
        float4 r;
        r.x = p[(size_t)(4 * n4 + 0) * M_DIM + m];
        r.y = p[(size_t)(4 * n4 + 1) * M_DIM + m];
        r.z = p[(size_t)(4 * n4 + 2) * M_DIM + m];
        r.w = p[(size_t)(4 * n4 + 3) * M_DIM + m];
        return r;
    }
}

template <bool T>
__global__ __launch_bounds__(256)
void lista_iter_kernel(const float* __restrict__ x, const float* __restrict__ Ap,
                       const float* __restrict__ Wp, const float* __restrict__ thr_all,
                       float* __restrict__ U, int iter, int kth) {
    __shared__ float u_s[8][1024];
    __shared__ float r_s[8][256];
    __shared__ float tau_s[8];
    const int tid = threadIdx.x;
    const int lane = tid & 63;
    const int wave = tid >> 6;
    const int row0 = blockIdx.x * 8;
    const float t = thr_all[iter];
    {
        const float4* Ug4 = (const float4*)(U + (size_t)row0 * N_DIM);
        float4* us4 = (float4*)(&u_s[0][0]);
#pragma unroll
        for (int c = 0; c < 8; ++c) us4[tid + 256 * c] = Ug4[tid + 256 * c];
    }
    __syncthreads();
    {
        double4 acc0 = {0, 0, 0, 0}, acc1 = {0, 0, 0, 0};
        const float4* u0p = (const float4*)&u_s[wave][0];
        const float4* u1p = (const float4*)&u_s[wave + 4][0];
        for (int n4 = 0; n4 < 256; ++n4) {
            float4 u0 = u0p[n4];
            float4 u1 = u1p[n4];
            float4 a0 = loadAT<T>(Ap, 4 * n4 + 0, lane);
            float4 a1 = loadAT<T>(Ap, 4 * n4 + 1, lane);
            float4 a2 = loadAT<T>(Ap, 4 * n4 + 2, lane);
            float4 a3 = loadAT<T>(Ap, 4 * n4 + 3, lane);
            DFMA4(acc0, u0.x, a0); DFMA4(acc0, u0.y, a1); DFMA4(acc0, u0.z, a2); DFMA4(acc0, u0.w, a3);
            DFMA4(acc1, u1.x, a0); DFMA4(acc1, u1.y, a1); DFMA4(acc1, u1.z, a2); DFMA4(acc1, u1.w, a3);
        }
        float4 xv0 = ((const float4*)(x + (size_t)(row0 + wave) * M_DIM))[lane];
        float4 xv1 = ((const float4*)(x + (size_t)(row0 + wave + 4) * M_DIM))[lane];
        float4 rv0, rv1;
        rv0.x = (float)((double)xv0.x - acc0.x);
        rv0.y = (float)((double)xv0.y - acc0.y);
        rv0.z = (float)((double)xv0.z - acc0.z);
        rv0.w = (float)((double)xv0.w - acc0.w);
        rv1.x = (float)((double)xv1.x - acc1.x);
        rv1.y = (float)((double)xv1.y - acc1.y);
        rv1.z = (float)((double)xv1.z - acc1.z);
        rv1.w = (float)((double)xv1.w - acc1.w);
        ((float4*)&r_s[wave][0])[lane] = rv0;
        ((float4*)&r_s[wave + 4][0])[lane] = rv1;
    }
    __syncthreads();
    {
        const float4* r0p = (const float4*)&r_s[wave][0];
        const float4* r1p = (const float4*)&r_s[wave + 4][0];
        float4* u0p = (float4*)&u_s[wave][0];
        float4* u1p = (float4*)&u_s[wave + 4][0];
#pragma unroll 1
        for (int q = 0; q < 4; ++q) {
            const int n4 = lane + 64 * q;
            double4 acc0 = {0, 0, 0, 0}, acc1 = {0, 0, 0, 0};
            for (int m4 = 0; m4 < 64; ++m4) {
                float4 r0 = r0p[m4];
                float4 r1 = r1p[m4];
                float4 w0 = loadWT<T>(Wp, 4 * m4 + 0, n4);
                float4 w1 = loadWT<T>(Wp, 4 * m4 + 1, n4);
                float4 w2 = loadWT<T>(Wp, 4 * m4 + 2, n4);
                float4 w3 = loadWT<T>(Wp, 4 * m4 + 3, n4);
                DFMA4(acc0, r0.x, w0); DFMA4(acc0, r0.y, w1); DFMA4(acc0, r0.z, w2); DFMA4(acc0, r0.w, w3);
                DFMA4(acc1, r1.x, w0); DFMA4(acc1, r1.y, w1); DFMA4(acc1, r1.z, w2); DFMA4(acc1, r1.w, w3);
            }
            float4 uv0 = u0p[n4];
            uv0.x = (float)((double)uv0.x + acc0.x);
            uv0.y = (float)((double)uv0.y + acc0.y);
            uv0.z = (float)((double)uv0.z + acc0.z);
            uv0.w = (float)((double)uv0.w + acc0.w);
            u0p[n4] = uv0;
            float4 uv1 = u1p[n4];
            uv1.x = (float)((double)uv1.x + acc1.x);
            uv1.y = (float)((double)uv1.y + acc1.y);
            uv1.z = (float)((double)uv1.z + acc1.z);
            uv1.w = (float)((double)uv1.w + acc1.w);
            u1p[n4] = uv1;
        }
    }
    __syncthreads();
    {
#pragma unroll 1
        for (int rr = 0; rr < 2; ++rr) {
            const int row = wave + rr * 4;
            unsigned key[16];
#pragma unroll
            for (int j = 0; j < 16; ++j)
                key[j] = __float_as_uint(u_s[row][lane + 64 * j]) & 0x7fffffffu;
            unsigned p = 0;
#pragma unroll 1
            for (int b = 30; b >= 0; --b) {
                const unsigned cand = p | (1u << b);
                int cnt = 0;
#pragma unroll
                for (int j = 0; j < 16; ++j) cnt += (key[j] >= cand) ? 1 : 0;
#pragma unroll
                for (int off = 32; off; off >>= 1) cnt += __shfl_xor(cnt, off);
                if (cnt >= kth) p = cand;
            }
            if (lane == 0) tau_s[row] = __uint_as_float(p);
        }
    }
    __syncthreads();
    {
        const float4* us4 = (const float4*)&u_s[0][0];
        float4* Uw = (float4*)(U + (size_t)row0 * N_DIM);
#pragma unroll 1
        for (int c = 0; c < 8; ++c) {
            const int idx = tid + 256 * c;
            const int row = idx >> 8;
            const float thrv = fmaxf(t, tau_s[row]);
            float4 v = us4[idx];
            float4 o;
            o.x = shrink_one(v.x, t, thrv);
            o.y = shrink_one(v.y, t, thrv);
            o.z = shrink_one(v.z, t, thrv);
            o.w = shrink_one(v.w, t, thrv);
            Uw[idx] = o;
        }
    }
}

// ================= launcher =================
extern "C" void kernel_launch(void* const* d_in, const int* in_sizes, int n_in,
                              void* d_out, int out_size, void* d_ws, size_t ws_size,
                              hipStream_t stream) {
    const float* x   = (const float*)d_in[0];  // [16384][256]
    const float* A   = (const float*)d_in[1];  // [256][1024]
    const float* W   = (const float*)d_in[2];  // [16][1024][256]
    const float* thr = (const float*)d_in[3];  // [16]

    float* UV = (float*)d_out;                 // v (pre-shrink) / u (post-spp) state

    static const int ktab[DEPTH] = {13, 25, 37, 50, 52, 52, 52, 52,
                                    52, 52, 52, 52, 52, 52, 52, 52};

    if (ws_size >= WS_FAST_NEED) {
        unsigned short* ATp = (unsigned short*)((char*)d_ws + ATP_OFF_B);
        unsigned short* WTp = (unsigned short*)((char*)d_ws + WTP_OFF_B);
        unsigned short* RP  = (unsigned short*)((char*)d_ws + RP_OFF_B);

        prep_a_kernel<<<128, 256, 0, stream>>>(A, ATp);
        prep_w_kernel<<<2048, 256, 0, stream>>>(W, WTp);
        prep_x_kernel<<<2048, 256, 0, stream>>>(x, RP);

        // iter 0: u=0, r=x (RP already holds frag(x))
        g2_kernel<<<2048, 1024, 0, stream>>>(RP, WTp, UV, 0);   // UV = v_0

        for (int it = 1; it < DEPTH; ++it) {
            // UV: v_{it-1} -> u_{it-1} (select + shrink in place)
            spp_kernel<<<B_ROWS / 16, 1024, 0, stream>>>(UV, thr, it - 1, ktab[it - 1]);
            // RP = frag(x - u * A^T)
            g1_kernel<<<512, 1024, 0, stream>>>(UV, x, ATp, RP);
            // UV = u + r * W^T = v_it
            g2_kernel<<<2048, 1024, 0, stream>>>(RP, WTp + (size_t)it * WTP_SLICE, UV, it);
        }
        s_kernel<<<B_ROWS / 8, 256, 0, stream>>>(UV, thr, DEPTH - 1, ktab[DEPTH - 1]);
    } else if (ws_size >= WS_OLD_NEED) {
        float* ws = (float*)d_ws;
        float* AT = ws + AT_OFF;
        float* WT = ws + WT_OFF;
        zero_kernel<<<1024, 256, 0, stream>>>(UV, B_ROWS * N_DIM);
        dim3 tb(32, 8);
        transpose_kernel<<<dim3(N_DIM / 32, M_DIM / 32, 1), tb, 0, stream>>>(A, AT, M_DIM, N_DIM);
        transpose_kernel<<<dim3(M_DIM / 32, N_DIM / 32, DEPTH), tb, 0, stream>>>(W, WT, N_DIM, M_DIM);
        for (int it = 0; it < DEPTH; ++it)
            lista_iter_kernel<true><<<B_ROWS / 8, 256, 0, stream>>>(
                x, AT, WT + (size_t)it * M_DIM * N_DIM, thr, UV, it, ktab[it]);
    } else {
        zero_kernel<<<1024, 256, 0, stream>>>(UV, B_ROWS * N_DIM);
        for (int it = 0; it < DEPTH; ++it)
            lista_iter_kernel<false><<<B_ROWS / 8, 256, 0, stream>>>(
                x, A, W + (size_t)it * N_DIM * M_DIM, thr, UV, it, ktab[it]);
    }
}

// Round 17
// 2954.433 us; speedup vs baseline: 1.3677x; 1.0670x over previous
//
#include <hip/hip_runtime.h>
#include <hip/hip_bf16.h>

#define B_ROWS 16384
#define M_DIM  256
#define N_DIM  1024
#define DEPTH  16

typedef __attribute__((ext_vector_type(8))) short short8;
typedef __attribute__((ext_vector_type(4))) float f32x4;
typedef __attribute__((ext_vector_type(2))) float f32x2;

// ---------------- fast path ws layout (bytes) ----------------
#define ATP_OFF_B   0
#define WTP_OFF_B   1572864
#define RP_OFF_B    (1572864 + 25165824)
#define TAU_OFF_B   (RP_OFF_B + 25165824)
#define WS_FAST_NEED ((size_t)TAU_OFF_B + 65536)
#define WTP_SLICE   (64 * 8 * 3 * 512)              // ushorts per iteration
#define RP_PANEL_US 24576                            // ushorts per 32-row panel (48KB)

// ---------------- fallback (round-3) ws layout ----------------
#define AT_OFF 0
#define WT_OFF (262144)
#define WS_OLD_NEED ((size_t)(262144 + 16 * 262144) * 4)

// ================= helpers =================
__device__ __forceinline__ unsigned short bf16r(float f) {
    unsigned u = __float_as_uint(f);
    u += 0x7fffu + ((u >> 16) & 1u);
    return (unsigned short)(u >> 16);
}
__device__ __forceinline__ float bf2f(unsigned short h) {
    return __uint_as_float(((unsigned)h) << 16);
}
__device__ __forceinline__ void split3(float x, unsigned short& h, unsigned short& m,
                                       unsigned short& lo) {
    h = bf16r(x); float r1 = x - bf2f(h);
    m = bf16r(r1); float r2 = r1 - bf2f(m);
    lo = bf16r(r2);
}
__device__ __forceinline__ f32x4 MF(short8 a, short8 b, f32x4 c) {
    return __builtin_amdgcn_mfma_f32_16x16x32_bf16(a, b, c, 0, 0, 0);
}
__device__ __forceinline__ float shrink_one(float v, float t, float thrv) {
    float a = fabsf(v);
    return (a >= thrv) ? v : copysignf(fmaxf(a - t, 0.0f), v);
}

// ================= prep kernels (frag-ordered bf16 planes) =================
__global__ void prep_a_kernel(const float* __restrict__ A, unsigned short* __restrict__ ATp) {
    int g = blockIdx.x * 256 + threadIdx.x;
    if (g >= 16 * 32 * 64) return;
    int l = g & 63, kc = (g >> 6) & 31, tile = g >> 11;
    int row = tile * 16 + (l & 15);
    int k0 = kc * 32 + ((l >> 4) << 3);
    unsigned short h[8], m[8], lo[8];
#pragma unroll
    for (int j = 0; j < 8; ++j) split3(A[(size_t)row * N_DIM + k0 + j], h[j], m[j], lo[j]);
    size_t base = ((size_t)(tile * 32 + kc) * 3) * 512 + l * 8;
#pragma unroll
    for (int j = 0; j < 8; ++j) {
        ATp[base + j] = h[j];
        ATp[base + 512 + j] = m[j];
        ATp[base + 1024 + j] = lo[j];
    }
}

__global__ void prep_w_kernel(const float* __restrict__ W, unsigned short* __restrict__ WTp) {
    int g = blockIdx.x * 256 + threadIdx.x;
    if (g >= 16 * 64 * 8 * 64) return;
    int l = g & 63, kc = (g >> 6) & 7, tile = (g >> 9) & 63, it = g >> 15;
    int n = tile * 16 + (l & 15);
    int m0 = kc * 32 + ((l >> 4) << 3);
    const float* Wi = W + (size_t)it * N_DIM * M_DIM;
    unsigned short h[8], m[8], lo[8];
#pragma unroll
    for (int j = 0; j < 8; ++j) split3(Wi[(size_t)n * M_DIM + m0 + j], h[j], m[j], lo[j]);
    size_t base = (((size_t)(it * 64 + tile) * 8 + kc) * 3) * 512 + l * 8;
#pragma unroll
    for (int j = 0; j < 8; ++j) {
        WTp[base + j] = h[j];
        WTp[base + 512 + j] = m[j];
        WTp[base + 1024 + j] = lo[j];
    }
}

// RP frag layout, panel-local: us = (((c*2+wm)*4+kc')*3 + p)*512 + l*8 + j
__global__ void prep_x_kernel(const float* __restrict__ x, unsigned short* __restrict__ RP) {
    int g = blockIdx.x * 256 + threadIdx.x;      // 524288
    if (g >= 524288) return;
    int l = g & 63, kcp = (g >> 6) & 3, wm = (g >> 8) & 1, c = (g >> 9) & 1, panel = g >> 10;
    int row = panel * 32 + wm * 16 + (l & 15);
    int k0 = c * 128 + kcp * 32 + ((l >> 4) << 3);
    unsigned short h[8], m[8], lo[8];
#pragma unroll
    for (int j = 0; j < 8; ++j) split3(x[(size_t)row * M_DIM + k0 + j], h[j], m[j], lo[j]);
    size_t base = (size_t)panel * RP_PANEL_US + ((((c * 2 + wm) * 4 + kcp) * 3)) * 512 + l * 8;
#pragma unroll
    for (int j = 0; j < 8; ++j) {
        RP[base + j] = h[j];
        RP[base + 512 + j] = m[j];
        RP[base + 1024 + j] = lo[j];
    }
}

// ================= STAU: exact per-row k-th largest of |v| -> TAU (read-only) =================
// 1 row/wave, 16 waves/block, 1024 blocks. Saves the 64MB/iter u-writeback:
// shrink is applied on the fly in g1 staging and g2 epilogue (r12-verified path).
__global__ __launch_bounds__(1024)
void stau_kernel(const float* __restrict__ UV, float* __restrict__ TAU, int kth) {
    const int l = threadIdx.x & 63;
    const int w = threadIdx.x >> 6;
    const int row = blockIdx.x * 16 + w;
    const float* vp = UV + (size_t)row * N_DIM;
    unsigned key[16];
#pragma unroll
    for (int j = 0; j < 16; ++j)
        key[j] = __float_as_uint(vp[l + 64 * j]) & 0x7fffffffu;
    unsigned p = 0;
#pragma unroll 1
    for (int b = 30; b >= 0; --b) {
        const unsigned cand = p | (1u << b);
        int cnt = 0;
#pragma unroll
        for (int j = 0; j < 16; ++j)
            cnt += __popcll(__ballot(key[j] >= cand));
        if (cnt >= kth) p = cand;       // uniform across lanes
    }
    if (l == 0) TAU[row] = __uint_as_float(p);
}

#define LSTR2 136    // staging row stride (ushorts)
#define BUFUS 13056  // one staging buffer = 3 planes * 32 rows * 136 us

// ================= G1: RP = frag(x - shrink(UV) * A^T)  (K = 1024) =================
// r13 geometry (grid 512, 1024 thr, 16 waves 2wm x 8wn, tt=2, BM=32, f64
// drains, dbuf staging, one barrier per chunk); staging applies shrink with
// (t_{it-1}, TAU) on the fly (UV holds pre-shrink v).
__global__ __launch_bounds__(1024)
void g1_kernel(const float* __restrict__ UV, const float* __restrict__ x,
               const unsigned short* __restrict__ ATp,
               const float* __restrict__ thr_all, const float* __restrict__ TAU,
               unsigned short* __restrict__ RP, int iter) {
    __align__(16) __shared__ unsigned short smem[2 * BUFUS];  // dbuf staging; epilogue img
    const int tid = threadIdx.x;
    const int l = tid & 63, w = tid >> 6;
    const int wm = w >> 3, wn = w & 7;
    const int panel = blockIdx.x;
    const int row0 = panel * 32;
    const int arow = 16 * wm + (l & 15);
    const int akl  = (l >> 4) << 3;
    const float tprev = thr_all[iter - 1];

    f32x4 acc_hi[2], acc_rest[2];
    double acc64[2][4];
#pragma unroll
    for (int t = 0; t < 2; ++t) {
        acc_hi[t] = (f32x4){0, 0, 0, 0};
        acc_rest[t] = (f32x4){0, 0, 0, 0};
#pragma unroll
        for (int e = 0; e < 4; ++e) acc64[t][e] = 0.0;
    }

    // per-thread staging geometry (row fixed per thread/jj -> hoist thrv)
    unsigned soff[2]; float thrv_r[2]; const float* uvp[2];
#pragma unroll
    for (int jj = 0; jj < 2; ++jj) {
        const int idx = tid + 1024 * jj;
        const int r = idx >> 6, kq = idx & 63;
        soff[jj] = (unsigned)r * LSTR2 + kq * 2;
        thrv_r[jj] = fmaxf(tprev, TAU[row0 + r]);
        uvp[jj] = UV + (size_t)(row0 + r) * N_DIM + kq * 2;
    }

    // ---- staging prologue: ch0 -> buf0; issue ch1 loads ----
    f32x2 st[2];
#pragma unroll
    for (int jj = 0; jj < 2; ++jj) st[jj] = *(const f32x2*)(uvp[jj]);
#pragma unroll
    for (int jj = 0; jj < 2; ++jj) {
        const float a0 = shrink_one(st[jj].x, tprev, thrv_r[jj]);
        const float a1 = shrink_one(st[jj].y, tprev, thrv_r[jj]);
        unsigned short h0, m0, lo0, h1, m1, lo1;
        split3(a0, h0, m0, lo0);
        split3(a1, h1, m1, lo1);
        *(unsigned*)&smem[soff[jj]] = (unsigned)h0 | ((unsigned)h1 << 16);
        *(unsigned*)&smem[4352 + soff[jj]] = (unsigned)m0 | ((unsigned)m1 << 16);
        *(unsigned*)&smem[8704 + soff[jj]] = (unsigned)lo0 | ((unsigned)lo1 << 16);
    }
#pragma unroll
    for (int jj = 0; jj < 2; ++jj) st[jj] = *(const f32x2*)(uvp[jj] + 128);
    __syncthreads();

    // ---- main loop: ONE barrier per chunk; staging of c+1 overlaps MFMA of c ----
    for (int c = 0; c < 8; ++c) {
        const unsigned bb = (unsigned)(c & 1) * BUFUS;
        const unsigned nb = (unsigned)((c + 1) & 1) * BUFUS;
        if (c < 7) {
#pragma unroll
            for (int jj = 0; jj < 2; ++jj) {
                const float a0 = shrink_one(st[jj].x, tprev, thrv_r[jj]);
                const float a1 = shrink_one(st[jj].y, tprev, thrv_r[jj]);
                unsigned short h0, m0, lo0, h1, m1, lo1;
                split3(a0, h0, m0, lo0);
                split3(a1, h1, m1, lo1);
                *(unsigned*)&smem[nb + soff[jj]] = (unsigned)h0 | ((unsigned)h1 << 16);
                *(unsigned*)&smem[nb + 4352 + soff[jj]] = (unsigned)m0 | ((unsigned)m1 << 16);
                *(unsigned*)&smem[nb + 8704 + soff[jj]] = (unsigned)lo0 | ((unsigned)lo1 << 16);
            }
        }
        if (c < 6) {
#pragma unroll
            for (int jj = 0; jj < 2; ++jj) st[jj] = *(const f32x2*)(uvp[jj] + (c + 2) * 128);
        }
#pragma unroll
        for (int kc = 0; kc < 4; ++kc) {
            const unsigned ao = bb + (unsigned)arow * LSTR2 + kc * 32 + akl;
            short8 ah = *(const short8*)&smem[ao];
            short8 am = *(const short8*)&smem[ao + 4352];
            short8 al = *(const short8*)&smem[ao + 8704];
#pragma unroll
            for (int tt = 0; tt < 2; ++tt) {
                const int tile = wn * 2 + tt;
                const unsigned bo = ((unsigned)(tile * 32 + c * 4 + kc) * 3) * 512 + l * 8;
                short8 bh = *(const short8*)&ATp[bo];
                short8 bm = *(const short8*)&ATp[bo + 512];
                short8 bl = *(const short8*)&ATp[bo + 1024];
                acc_hi[tt] = MF(ah, bh, acc_hi[tt]);
                acc_rest[tt] = MF(ah, bm, acc_rest[tt]);
                acc_rest[tt] = MF(am, bh, acc_rest[tt]);
                acc_rest[tt] = MF(am, bm, acc_rest[tt]);
                acc_rest[tt] = MF(ah, bl, acc_rest[tt]);
                acc_rest[tt] = MF(al, bh, acc_rest[tt]);
            }
        }
#pragma unroll
        for (int tt = 0; tt < 2; ++tt) {    // drain once per 128-k chunk
#pragma unroll
            for (int e = 0; e < 4; ++e) acc64[tt][e] += (double)acc_hi[tt][e];
            acc_hi[tt] = (f32x4){0, 0, 0, 0};
        }
        __syncthreads();                    // one barrier per chunk
    }

    // ---- epilogue: r -> split3 -> frag image in LDS -> linear dump to RP ----
    {
        const int cimg = wn >> 2, kcp = wn & 3;
        const unsigned fbase = ((((unsigned)(cimg * 2 + wm) * 4 + kcp) * 3)) * 512;
#pragma unroll
        for (int tt = 0; tt < 2; ++tt) {
            const int col = wn * 32 + tt * 16 + (l & 15);
            const int hi2 = (tt * 2 + ((l & 15) >> 3)) & 3;
#pragma unroll
            for (int e = 0; e < 4; ++e) {
                const int rl = ((l >> 4) << 2) + e;          // row_local & 15
                const int row = row0 + wm * 16 + rl;
                const double tot = acc64[tt][e] + (double)acc_rest[tt][e];
                const float rv = (float)((double)x[(size_t)row * M_DIM + col] - tot);
                unsigned short h, m, lo;
                split3(rv, h, m, lo);
                const unsigned sl = fbase + (unsigned)(hi2 * 16 + rl) * 8 + (l & 7);
                smem[sl] = h;
                smem[sl + 512] = m;
                smem[sl + 1024] = lo;
            }
        }
    }
    __syncthreads();
    {
        // panel image = 24576 us = 3072 uint4 = 3 x 1024
        const uint4* s4 = (const uint4*)smem;
        uint4* d4 = (uint4*)(RP + (size_t)panel * RP_PANEL_US);
        d4[tid] = s4[tid];
        d4[tid + 1024] = s4[tid + 1024];
        d4[tid + 2048] = s4[tid + 2048];
    }
}

// ================= G2: UV = shrink(UV) + r * W_i^T  (K = 256) =================
// r13 structure; epilogue applies shrink with (t_{it-1}, TAU) before adding
// (UV holds pre-shrink v; r12-verified epilogue).
__global__ __launch_bounds__(1024)
void g2_kernel(const unsigned short* __restrict__ RP, const unsigned short* __restrict__ WTpi,
               const float* __restrict__ thr_all, const float* __restrict__ TAU,
               float* UV, int iter) {
    __align__(16) __shared__ unsigned short img[24576];
    const int tid = threadIdx.x;
    const int l = tid & 63, w = tid >> 6;
    const int wm = w >> 3, wn = w & 7;
    const int panel = blockIdx.x >> 2, cg = blockIdx.x & 3;
    const int row0 = panel * 32;

    {   // copy 48KB RP panel -> LDS (pure copy)
        const uint4* s4 = (const uint4*)(RP + (size_t)panel * RP_PANEL_US);
        uint4* d4 = (uint4*)img;
        d4[tid] = s4[tid];
        d4[tid + 1024] = s4[tid + 1024];
        d4[tid + 2048] = s4[tid + 2048];
    }
    __syncthreads();

    f32x4 hi[2], rest[2], sum[2];
#pragma unroll
    for (int t = 0; t < 2; ++t) {
        hi[t] = (f32x4){0, 0, 0, 0};
        rest[t] = (f32x4){0, 0, 0, 0};
        sum[t] = (f32x4){0, 0, 0, 0};
    }

    for (int kc = 0; kc < 8; ++kc) {
        const unsigned ab = ((((unsigned)(kc >> 2) * 2 + wm) * 4 + (kc & 3)) * 3) * 512 + l * 8;
        short8 ah = *(const short8*)&img[ab];
        short8 am = *(const short8*)&img[ab + 512];
        short8 al = *(const short8*)&img[ab + 1024];
#pragma unroll
        for (int tt = 0; tt < 2; ++tt) {
            const int tile = cg * 16 + wn * 2 + tt;
            const unsigned bo = ((unsigned)(tile * 8 + kc) * 3) * 512 + l * 8;
            short8 bh = *(const short8*)&WTpi[bo];
            short8 bm = *(const short8*)&WTpi[bo + 512];
            short8 bl = *(const short8*)&WTpi[bo + 1024];
            hi[tt] = MF(ah, bh, hi[tt]);
            rest[tt] = MF(ah, bm, rest[tt]);
            rest[tt] = MF(am, bh, rest[tt]);
            rest[tt] = MF(am, bm, rest[tt]);
            rest[tt] = MF(ah, bl, rest[tt]);
            rest[tt] = MF(al, bh, rest[tt]);
        }
        if ((kc & 3) == 3) {
#pragma unroll
            for (int tt = 0; tt < 2; ++tt) {
#pragma unroll
                for (int e = 0; e < 4; ++e) sum[tt][e] += hi[tt][e];
                hi[tt] = (f32x4){0, 0, 0, 0};
            }
        }
    }

    const float tprev = (iter > 0) ? thr_all[iter - 1] : 0.0f;
#pragma unroll
    for (int tt = 0; tt < 2; ++tt) {
        const int col = cg * 256 + wn * 32 + tt * 16 + (l & 15);
#pragma unroll
        for (int e = 0; e < 4; ++e) {
            const int row = row0 + wm * 16 + ((l >> 4) << 2) + e;
            const float tot = sum[tt][e] + rest[tt][e];
            float us = 0.0f;
            if (iter > 0) {
                const float uo = UV[(size_t)row * N_DIM + col];
                const float thrv = fmaxf(tprev, TAU[row]);
                us = shrink_one(uo, tprev, thrv);
            }
            UV[(size_t)row * N_DIM + col] = us + tot;
        }
    }
}

// ================= final: full select + shrink, in place =================
__global__ __launch_bounds__(256)
void s_kernel(float* UV, const float* __restrict__ thr_all, int iter, int kth) {
    __shared__ float v_s[8][1024];
    __shared__ float tau_s[8];
    const int tid = threadIdx.x;
    const int lane = tid & 63;
    const int wave = tid >> 6;
    const int row0 = blockIdx.x * 8;
    const float t = thr_all[iter];
    {
        const float4* Vg4 = (const float4*)(UV + (size_t)row0 * N_DIM);
        float4* vs4 = (float4*)(&v_s[0][0]);
#pragma unroll
        for (int c = 0; c < 8; ++c) vs4[tid + 256 * c] = Vg4[tid + 256 * c];
    }
    __syncthreads();
#pragma unroll 1
    for (int rr = 0; rr < 2; ++rr) {
        const int row = wave + rr * 4;
        unsigned key[16];
#pragma unroll
        for (int j = 0; j < 16; ++j)
            key[j] = __float_as_uint(v_s[row][lane + 64 * j]) & 0x7fffffffu;
        unsigned p = 0;
#pragma unroll 1
        for (int b = 30; b >= 0; --b) {
            const unsigned cand = p | (1u << b);
            int cnt = 0;
#pragma unroll
            for (int j = 0; j < 16; ++j) cnt += (key[j] >= cand) ? 1 : 0;
#pragma unroll
            for (int off = 32; off; off >>= 1) cnt += __shfl_xor(cnt, off);
            if (cnt >= kth) p = cand;
        }
        if (lane == 0) tau_s[row] = __uint_as_float(p);
    }
    __syncthreads();
    {
        const float4* vs4 = (const float4*)&v_s[0][0];
        float4* Uw = (float4*)(UV + (size_t)row0 * N_DIM);
#pragma unroll 1
        for (int c = 0; c < 8; ++c) {
            const int idx = tid + 256 * c;
            const int row = idx >> 8;
            const float thrv = fmaxf(t, tau_s[row]);
            float4 v = vs4[idx];
            float4 o;
            o.x = shrink_one(v.x, t, thrv);
            o.y = shrink_one(v.y, t, thrv);
            o.z = shrink_one(v.z, t, thrv);
            o.w = shrink_one(v.w, t, thrv);
            Uw[idx] = o;
        }
    }
}

// ===================== round-3 fallback kernels ======================
#define DFMA4(acc, s, v) do { \
    (acc).x += (double)(s) * (double)(v).x; \
    (acc).y += (double)(s) * (double)(v).y; \
    (acc).z += (double)(s) * (double)(v).z; \
    (acc).w += (double)(s) * (double)(v).w; } while (0)

__global__ void transpose_kernel(const float* __restrict__ in, float* __restrict__ out,
                                 int R, int C) {
    __shared__ float tile[32][33];
    int s = blockIdx.z;
    const float* ip = in + (size_t)s * R * C;
    float* op = out + (size_t)s * R * C;
    int c0 = blockIdx.x * 32, r0 = blockIdx.y * 32;
    int tx = threadIdx.x, ty = threadIdx.y;
#pragma unroll
    for (int k = 0; k < 4; ++k)
        tile[ty + 8 * k][tx] = ip[(size_t)(r0 + ty + 8 * k) * C + (c0 + tx)];
    __syncthreads();
#pragma unroll
    for (int k = 0; k < 4; ++k)
        op[(size_t)(c0 + ty + 8 * k) * R + (r0 + tx)] = tile[tx][ty + 8 * k];
}

__global__ void zero_kernel(float* __restrict__ p, int n) {
    int i = blockIdx.x * blockDim.x + threadIdx.x;
    int stride = gridDim.x * blockDim.x;
    for (; i < n; i += stride) p[i] = 0.0f;
}

template <bool T>
__device__ __forceinline__ float4 loadAT(const float* __restrict__ p, int n, int m4) {
    if constexpr (T) {
        return ((const float4*)p)[n * 64 + m4];
    } else {
        float4 r;
        r.x = p[(size_t)(4 * m4 + 0) * N_DIM + n];
        r.y = p[(size_t)(4 * m4 + 1) * N_DIM + n];
        r.z = p[(size_t)(4 * m4 + 2) * N_DIM + n];
        r.w = p[(size_t)(4 * m4 + 3) * N_DIM + n];
        return r;
    }
}
template <bool T>
__device__ __forceinline__ float4 loadWT(const float* __restrict__ p, int m, int n4) {
    if constexpr (T) {
        return ((const float4*)p)[m * 256 + n4];
    } else {
        float4 r;
        r.x = p[(size_t)(4 * n4 + 0) * M_DIM + m];
        r.y = p[(size_t)(4 * n4 + 1) * M_DIM + m];
        r.z = p[(size_t)(4 * n4 + 2) * M_DIM + m];
        r.w = p[(size_t)(4 * n4 + 3) * M_DIM + m];
        return r;
    }
}

template <bool T>
__global__ __launch_bounds__(256)
void lista_iter_kernel(const float* __restrict__ x, const float* __restrict__ Ap,
                       const float* __restrict__ Wp, const float* __restrict__ thr_all,
                       float* __restrict__ U, int iter, int kth) {
    __shared__ float u_s[8][1024];
    __shared__ float r_s[8][256];
    __shared__ float tau_s[8];
    const int tid = threadIdx.x;
    const int lane = tid & 63;
    const int wave = tid >> 6;
    const int row0 = blockIdx.x * 8;
    const float t = thr_all[iter];
    {
        const float4* Ug4 = (const float4*)(U + (size_t)row0 * N_DIM);
        float4* us4 = (float4*)(&u_s[0][0]);
#pragma unroll
        for (int c = 0; c < 8; ++c) us4[tid + 256 * c] = Ug4[tid + 256 * c];
    }
    __syncthreads();
    {
        double4 acc0 = {0, 0, 0, 0}, acc1 = {0, 0, 0, 0};
        const float4* u0p = (const float4*)&u_s[wave][0];
        const float4* u1p = (const float4*)&u_s[wave + 4][0];
        for (int n4 = 0; n4 < 256; ++n4) {
            float4 u0 = u0p[n4];
            float4 u1 = u1p[n4];
            float4 a0 = loadAT<T>(Ap, 4 * n4 + 0, lane);
            float4 a1 = loadAT<T>(Ap, 4 * n4 + 1, lane);
            float4 a2 = loadAT<T>(Ap, 4 * n4 + 2, lane);
            float4 a3 = loadAT<T>(Ap, 4 * n4 + 3, lane);
            DFMA4(acc0, u0.x, a0); DFMA4(acc0, u0.y, a1); DFMA4(acc0, u0.z, a2); DFMA4(acc0, u0.w, a3);
            DFMA4(acc1, u1.x, a0); DFMA4(acc1, u1.y, a1); DFMA4(acc1, u1.z, a2); DFMA4(acc1, u1.w, a3);
        }
        float4 xv0 = ((const float4*)(x + (size_t)(row0 + wave) * M_DIM))[lane];
        float4 xv1 = ((const float4*)(x + (size_t)(row0 + wave + 4) * M_DIM))[lane];
        float4 rv0, rv1;
        rv0.x = (float)((double)xv0.x - acc0.x);
        rv0.y = (float)((double)xv0.y - acc0.y);
        rv0.z = (float)((double)xv0.z - acc0.z);
        rv0.w = (float)((double)xv0.w - acc0.w);
        rv1.x = (float)((double)xv1.x - acc1.x);
        rv1.y = (float)((double)xv1.y - acc1.y);
        rv1.z = (float)((double)xv1.z - acc1.z);
        rv1.w = (float)((double)xv1.w - acc1.w);
        ((float4*)&r_s[wave][0])[lane] = rv0;
        ((float4*)&r_s[wave + 4][0])[lane] = rv1;
    }
    __syncthreads();
    {
        const float4* r0p = (const float4*)&r_s[wave][0];
        const float4* r1p = (const float4*)&r_s[wave + 4][0];
        float4* u0p = (float4*)&u_s[wave][0];
        float4* u1p = (float4*)&u_s[wave + 4][0];
#pragma unroll 1
        for (int q = 0; q < 4; ++q) {
            const int n4 = lane + 64 * q;
            double4 acc0 = {0, 0, 0, 0}, acc1 = {0, 0, 0, 0};
            for (int m4 = 0; m4 < 64; ++m4) {
                float4 r0 = r0p[m4];
                float4 r1 = r1p[m4];
                float4 w0 = loadWT<T>(Wp, 4 * m4 + 0, n4);
                float4 w1 = loadWT<T>(Wp, 4 * m4 + 1, n4);
                float4 w2 = loadWT<T>(Wp, 4 * m4 + 2, n4);
                float4 w3 = loadWT<T>(Wp, 4 * m4 + 3, n4);
                DFMA4(acc0, r0.x, w0); DFMA4(acc0, r0.y, w1); DFMA4(acc0, r0.z, w2); DFMA4(acc0, r0.w, w3);
                DFMA4(acc1, r1.x, w0); DFMA4(acc1, r1.y, w1); DFMA4(acc1, r1.z, w2); DFMA4(acc1, r1.w, w3);
            }
            float4 uv0 = u0p[n4];
            uv0.x = (float)((double)uv0.x + acc0.x);
            uv0.y = (float)((double)uv0.y + acc0.y);
            uv0.z = (float)((double)uv0.z + acc0.z);
            uv0.w = (float)((double)uv0.w + acc0.w);
            u0p[n4] = uv0;
            float4 uv1 = u1p[n4];
            uv1.x = (float)((double)uv1.x + acc1.x);
            uv1.y = (float)((double)uv1.y + acc1.y);
            uv1.z = (float)((double)uv1.z + acc1.z);
            uv1.w = (float)((double)uv1.w + acc1.w);
            u1p[n4] = uv1;
        }
    }
    __syncthreads();
    {
#pragma unroll 1
        for (int rr = 0; rr < 2; ++rr) {
            const int row = wave + rr * 4;
            unsigned key[16];
#pragma unroll
            for (int j = 0; j < 16; ++j)
                key[j] = __float_as_uint(u_s[row][lane + 64 * j]) & 0x7fffffffu;
            unsigned p = 0;
#pragma unroll 1
            for (int b = 30; b >= 0; --b) {
                const unsigned cand = p | (1u << b);
                int cnt = 0;
#pragma unroll
                for (int j = 0; j < 16; ++j) cnt += (key[j] >= cand) ? 1 : 0;
#pragma unroll
                for (int off = 32; off; off >>= 1) cnt += __shfl_xor(cnt, off);
                if (cnt >= kth) p = cand;
            }
            if (lane == 0) tau_s[row] = __uint_as_float(p);
        }
    }
    __syncthreads();
    {
        const float4* us4 = (const float4*)&u_s[0][0];
        float4* Uw = (float4*)(U + (size_t)row0 * N_DIM);
#pragma unroll 1
        for (int c = 0; c < 8; ++c) {
            const int idx = tid + 256 * c;
            const int row = idx >> 8;
            const float thrv = fmaxf(t, tau_s[row]);
            float4 v = us4[idx];
            float4 o;
            o.x = shrink_one(v.x, t, thrv);
            o.y = shrink_one(v.y, t, thrv);
            o.z = shrink_one(v.z, t, thrv);
            o.w = shrink_one(v.w, t, thrv);
            Uw[idx] = o;
        }
    }
}

// ================= launcher =================
extern "C" void kernel_launch(void* const* d_in, const int* in_sizes, int n_in,
                              void* d_out, int out_size, void* d_ws, size_t ws_size,
                              hipStream_t stream) {
    const float* x   = (const float*)d_in[0];  // [16384][256]
    const float* A   = (const float*)d_in[1];  // [256][1024]
    const float* W   = (const float*)d_in[2];  // [16][1024][256]
    const float* thr = (const float*)d_in[3];  // [16]

    float* UV = (float*)d_out;                 // pre-shrink v state / final u (f32)

    static const int ktab[DEPTH] = {13, 25, 37, 50, 52, 52, 52, 52,
                                    52, 52, 52, 52, 52, 52, 52, 52};

    if (ws_size >= WS_FAST_NEED) {
        unsigned short* ATp = (unsigned short*)((char*)d_ws + ATP_OFF_B);
        unsigned short* WTp = (unsigned short*)((char*)d_ws + WTP_OFF_B);
        unsigned short* RP  = (unsigned short*)((char*)d_ws + RP_OFF_B);
        float* TAU = (float*)((char*)d_ws + TAU_OFF_B);

        prep_a_kernel<<<128, 256, 0, stream>>>(A, ATp);
        prep_w_kernel<<<2048, 256, 0, stream>>>(W, WTp);
        prep_x_kernel<<<2048, 256, 0, stream>>>(x, RP);

        // iter 0: u=0, r=x (RP already holds frag(x))
        g2_kernel<<<2048, 1024, 0, stream>>>(RP, WTp, thr, TAU, UV, 0);  // UV = v_0

        for (int it = 1; it < DEPTH; ++it) {
            // TAU = tau(v_{it-1}); UV stays pre-shrink
            stau_kernel<<<B_ROWS / 16, 1024, 0, stream>>>(UV, TAU, ktab[it - 1]);
            // RP = frag(x - shrink(v_{it-1}) * A^T)
            g1_kernel<<<512, 1024, 0, stream>>>(UV, x, ATp, thr, TAU, RP, it);
            // UV = shrink(v_{it-1}) + r * W^T = v_it
            g2_kernel<<<2048, 1024, 0, stream>>>(RP, WTp + (size_t)it * WTP_SLICE,
                                                 thr, TAU, UV, it);
        }
        s_kernel<<<B_ROWS / 8, 256, 0, stream>>>(UV, thr, DEPTH - 1, ktab[DEPTH - 1]);
    } else if (ws_size >= WS_OLD_NEED) {
        float* ws = (float*)d_ws;
        float* AT = ws + AT_OFF;
        float* WT = ws + WT_OFF;
        zero_kernel<<<1024, 256, 0, stream>>>(UV, B_ROWS * N_DIM);
        dim3 tb(32, 8);
        transpose_kernel<<<dim3(N_DIM / 32, M_DIM / 32, 1), tb, 0, stream>>>(A, AT, M_DIM, N_DIM);
        transpose_kernel<<<dim3(M_DIM / 32, N_DIM / 32, DEPTH), tb, 0, stream>>>(W, WT, N_DIM, M_DIM);
        for (int it = 0; it < DEPTH; ++it)
            lista_iter_kernel<true><<<B_ROWS / 8, 256, 0, stream>>>(
                x, AT, WT + (size_t)it * M_DIM * N_DIM, thr, UV, it, ktab[it]);
    } else {
        zero_kernel<<<1024, 256, 0, stream>>>(UV, B_ROWS * N_DIM);
        for (int it = 0; it < DEPTH; ++it)
            lista_iter_kernel<false><<<B_ROWS / 8, 256, 0, stream>>>(
                x, A, W + (size_t)it * N_DIM * M_DIM, thr, UV, it, ktab[it]);
    }
}